// Round 7
// baseline (438.277 us; speedup 1.0000x reference)
//
#include <hip/hip_runtime.h>
#include <math.h>

#define NNODES 50000
#define NEDGES 800000
#define DIN    256
#define DHID   128
#define NCLS   40

#define BW    128                    // dst values per bucket
#define NBK   391                    // ceil(NNODES / BW)
#define CAP   6144                   // LDS col capacity per bucket (mean 2048, sd ~45)
#define PPART 128                    // partition blocks per view
#define CHUNK 6250                   // NEDGES / PPART

// ---------------- fc1: x1 = relu(X @ W1 + b1) + fused row-norm ---------------
__global__ __launch_bounds__(256) void fc1_kernel(
    const float* __restrict__ X, const float* __restrict__ W1,
    const float* __restrict__ b1, float* __restrict__ x1,
    float* __restrict__ inv1)
{
  __shared__ float Xs[16][DIN];      // 16 KB
  __shared__ float ssrow[16];
  const int tid   = threadIdx.x;
  const int node0 = blockIdx.x * 16;

  if (tid < 16) ssrow[tid] = 0.f;
  const float4* Xv  = (const float4*)(X + (size_t)node0 * DIN);
  float4*       Xsv = (float4*)(&Xs[0][0]);
#pragma unroll
  for (int t = 0; t < 4; ++t) Xsv[tid + t * 256] = Xv[tid + t * 256];
  __syncthreads();

  const int h  = tid & 127;
  const int tm = tid >> 7;           // 0..1 -> node groups of 8
  float acc[8];
#pragma unroll
  for (int r = 0; r < 8; ++r) acc[r] = 0.f;

  for (int k = 0; k < DIN; k += 4) {
    const float w0 = W1[(k + 0) * DHID + h];
    const float w1 = W1[(k + 1) * DHID + h];
    const float w2 = W1[(k + 2) * DHID + h];
    const float w3 = W1[(k + 3) * DHID + h];
#pragma unroll
    for (int r = 0; r < 8; ++r) {
      const float4 xv = *(const float4*)&Xs[tm * 8 + r][k];   // ds_read_b128 broadcast
      acc[r] += xv.x * w0 + xv.y * w1 + xv.z * w2 + xv.w * w3;
    }
  }
  const float bb   = b1[h];
  const int   lane = tid & 63;
#pragma unroll
  for (int r = 0; r < 8; ++r) {
    float v = acc[r] + bb;
    v = v > 0.f ? v : 0.f;
    x1[(size_t)(node0 + tm * 8 + r) * DHID + h] = v;
    float q = v * v;                 // fused norm: reduce over 128 cols (2 waves)
#pragma unroll
    for (int off = 32; off; off >>= 1) q += __shfl_xor(q, off);
    if (lane == 0) atomicAdd(&ssrow[tm * 8 + r], q);   // exactly 2 adds/row: commutative
  }
  __syncthreads();
  if (tid < 16) inv1[node0 + tid] = 1.0f / fmaxf(sqrtf(ssrow[tid]), 1e-12f);
}

// ---------------- fc2: out = x3 @ W2 + b2, 8 nodes/block (320 thr) -----------
__global__ __launch_bounds__(320) void fc2_kernel(
    const float* __restrict__ x3, const float* __restrict__ W2,
    const float* __restrict__ b2, float* __restrict__ out)
{
  __shared__ float Xs[8][DHID];      // 4 KB
  const int tid   = threadIdx.x;
  const int node0 = blockIdx.x * 8;
  for (int idx = tid; idx < 8 * DHID; idx += 320)
    Xs[idx >> 7][idx & 127] = x3[(size_t)node0 * DHID + idx];
  __syncthreads();

  const int ns = tid / NCLS;         // 0..7
  const int c  = tid - ns * NCLS;    // 0..39
  float acc = b2[c];
#pragma unroll 8
  for (int k = 0; k < DHID; ++k) acc += Xs[ns][k] * W2[k * NCLS + c];
  out[(size_t)(node0 + ns) * NCLS + c] = acc;
}

// ---------------- CSR build: deterministic two-pass multi-split --------------
// K1: per-(view,block) LDS histogram of a private edge chunk -> H[v][bkt][blk]
__global__ __launch_bounds__(256) void hist_part_kernel(
    const int* __restrict__ dst1, const int* __restrict__ dst2,
    int* __restrict__ H)
{
  const int bid = blockIdx.x;
  const int v   = bid >= PPART;
  const int p   = v ? bid - PPART : bid;
  const int* __restrict__ dst = v ? dst2 : dst1;

  __shared__ int hist[NBK];
  for (int i = threadIdx.x; i < NBK; i += 256) hist[i] = 0;
  __syncthreads();
  const int beg = p * CHUNK;
  const int end = (beg + CHUNK < NEDGES) ? beg + CHUNK : NEDGES;
  for (int j = beg + threadIdx.x; j < end; j += 256)
    atomicAdd(&hist[dst[j] >> 7], 1);
  __syncthreads();
  for (int i = threadIdx.x; i < NBK; i += 256)
    H[(v * NBK + i) * PPART + p] = hist[i];
}

// K2a: per-bucket exclusive scan of its 128 partition counts (in place) + total
__global__ __launch_bounds__(128) void scan_bucket_kernel(
    int* __restrict__ H, int* __restrict__ btot)
{
  const int b   = blockIdx.x;        // 0..2*NBK-1
  const int tid = threadIdx.x;
  __shared__ int sm[PPART];
  const int v = H[b * PPART + tid];
  sm[tid] = v;
  __syncthreads();
  for (int off = 1; off < PPART; off <<= 1) {
    int t = (tid >= off) ? sm[tid - off] : 0;
    __syncthreads();
    sm[tid] += t;
    __syncthreads();
  }
  H[b * PPART + tid] = sm[tid] - v;  // exclusive within bucket
  if (tid == PPART - 1) btot[b] = sm[tid];
}

// K2b: scan 2*NBK bucket totals -> boffG (global bucket bases)
__global__ __launch_bounds__(1024) void scan_btot_kernel(
    const int* __restrict__ btot, int* __restrict__ boffG)
{
  __shared__ int sm[1024];
  const int tid = threadIdx.x;
  const int v = (tid < 2 * NBK) ? btot[tid] : 0;
  sm[tid] = v;
  __syncthreads();
  for (int off = 1; off < 1024; off <<= 1) {
    int t = (tid >= off) ? sm[tid - off] : 0;
    __syncthreads();
    sm[tid] += t;
    __syncthreads();
  }
  if (tid < 2 * NBK) boffG[tid] = sm[tid] - v;
  if (tid == 0) boffG[2 * NBK] = 2 * NEDGES;
}

// K3: place edges at exact positions (LDS cursors only; writes cluster ~128B)
__global__ __launch_bounds__(256) void scatter_part_kernel(
    const int* __restrict__ src1, const int* __restrict__ dst1,
    const int* __restrict__ src2, const int* __restrict__ dst2,
    const int* __restrict__ H, const int* __restrict__ boffG,
    int2* __restrict__ st)
{
  const int bid = blockIdx.x;
  const int v   = bid >= PPART;
  const int p   = v ? bid - PPART : bid;
  const int* __restrict__ src = v ? src2 : src1;
  const int* __restrict__ dst = v ? dst2 : dst1;

  __shared__ int lcur[NBK];
  for (int i = threadIdx.x; i < NBK; i += 256)
    lcur[i] = boffG[v * NBK + i] + H[(v * NBK + i) * PPART + p];
  __syncthreads();
  const int beg = p * CHUNK;
  const int end = (beg + CHUNK < NEDGES) ? beg + CHUNK : NEDGES;
  for (int j = beg + threadIdx.x; j < end; j += 256) {
    const int s = src[j], d = dst[j];
    const int k = atomicAdd(&lcur[d >> 7], 1);
    st[k] = make_int2(s, d);
  }
}

// K4: per bucket: degrees -> rp, place srcs in LDS, sort segments (determinism),
//     coalesced col write.
__global__ __launch_bounds__(256) void build_buckets_kernel(
    const int2* __restrict__ st, const int* __restrict__ boffG,
    int* __restrict__ rp1, int* __restrict__ rp2,
    int* __restrict__ col1, int* __restrict__ col2)
{
  const int bid = blockIdx.x;
  const int v   = bid >= NBK;
  const int b   = v ? bid - NBK : bid;
  int* __restrict__ rp  = v ? rp2 : rp1;
  int* __restrict__ col = v ? col2 : col1;
  const int tid = threadIdx.x;

  const int off0G  = boffG[bid];
  const int cnt    = boffG[bid + 1] - off0G;
  const int off0   = off0G - v * NEDGES;    // view-local offset
  const int base_d = b * BW;
  const int nd     = (NNODES - base_d < BW) ? (NNODES - base_d) : BW;

  __shared__ int deg[BW];
  __shared__ int loff[BW + 1];
  __shared__ int cur[BW];
  __shared__ int lcol[CAP];

  if (tid < BW) deg[tid] = 0;
  __syncthreads();
  for (int j = tid; j < cnt; j += 256)
    atomicAdd(&deg[st[off0G + j].y - base_d], 1);
  __syncthreads();

  if (tid == 0) loff[0] = 0;
  if (tid < BW) loff[tid + 1] = deg[tid];
  __syncthreads();
  for (int off = 1; off < BW; off <<= 1) {
    int t = (tid < BW && tid + 1 >= off) ? loff[tid + 1 - off] : 0;
    __syncthreads();
    if (tid < BW && tid + 1 >= off) loff[tid + 1] += t;
    __syncthreads();
  }
  if (tid < nd) rp[base_d + tid] = off0 + loff[tid];
  if (tid == 0 && b == NBK - 1) rp[NNODES] = NEDGES;
  if (tid < BW) cur[tid] = loff[tid];
  __syncthreads();

  if (cnt <= CAP) {
    for (int j = tid; j < cnt; j += 256) {
      const int2 pr = st[off0G + j];
      const int k = atomicAdd(&cur[pr.y - base_d], 1);
      lcol[k] = pr.x;
    }
    __syncthreads();
    if (tid < nd) {                   // sort own segment ascending (in LDS)
      const int s0 = loff[tid], s1 = s0 + deg[tid];
      for (int a = s0 + 1; a < s1; ++a) {
        const int key = lcol[a];
        int c = a - 1;
        while (c >= s0 && lcol[c] > key) { lcol[c + 1] = lcol[c]; --c; }
        lcol[c + 1] = key;
      }
    }
    __syncthreads();
    for (int j = tid; j < cnt; j += 256) col[off0 + j] = lcol[j];
  } else {                            // overflow fallback (never for random data)
    for (int j = tid; j < cnt; j += 256) {
      const int2 pr = st[off0G + j];
      const int k = atomicAdd(&cur[pr.y - base_d], 1);
      col[off0 + k] = pr.x;
    }
    __syncthreads();
    if (tid < nd) {
      const int s0 = off0 + loff[tid], s1 = s0 + deg[tid];
      for (int a = s0 + 1; a < s1; ++a) {
        const int key = col[a];
        int c = a - 1;
        while (c >= s0 && col[c] > key) { col[c + 1] = col[c]; --c; }
        col[c + 1] = key;
      }
    }
  }
}

// ---------------- AGNN layer: wave/node, 8 edges in flight (8-lane groups) ---
// softmax shift-invariance: w = exp(e) directly (|e| <= |beta|), identical to
// the reference's max-subtracted softmax up to fp32 rounding. Optionally fuses
// the output row-norm (inv_out) for the next layer.
__global__ __launch_bounds__(256) void agnn_layer_kernel(
    const float* __restrict__ x, const float* __restrict__ inv,
    const int* __restrict__ rp1, const int* __restrict__ col1,
    const int* __restrict__ rp2, const int* __restrict__ col2,
    const float* __restrict__ beta_p, const float* __restrict__ order_attn,
    float* __restrict__ y_out, float* __restrict__ inv_out, int n)
{
  const int wid  = (blockIdx.x * blockDim.x + threadIdx.x) >> 6;
  if (wid >= n) return;
  const int lane = threadIdx.x & 63;
  const int grp  = lane >> 3;        // 0..7 : which edge of the 8 in flight
  const int sub  = lane & 7;         // 0..7 : 16 dims each -> 128 dims

  const float beta = beta_p[0];
  const float bi   = beta * inv[wid];

  const float* xd_p = x + (size_t)wid * DHID + sub * 16;
  const float4 xd0 = *(const float4*)(xd_p);
  const float4 xd1 = *(const float4*)(xd_p + 4);
  const float4 xd2 = *(const float4*)(xd_p + 8);
  const float4 xd3 = *(const float4*)(xd_p + 12);

  float acc[16];
#pragma unroll
  for (int k = 0; k < 16; ++k) acc[k] = 0.f;

#pragma unroll
  for (int view = 0; view < 2; ++view) {
    const int*  rp   = view ? rp2 : rp1;
    const int*  col  = view ? col2 : col1;
    const float coef = order_attn[view];
    const int beg = rp[wid], end = rp[wid + 1];

    float s = 0.f;
    float yv[16];
#pragma unroll
    for (int k = 0; k < 16; ++k) yv[k] = 0.f;

    for (int j = beg + grp; j < end; j += 8) {
      const int   sa  = col[j];
      const float isa = inv[sa];
      const float* xs_p = x + (size_t)sa * DHID + sub * 16;
      const float4 a0 = *(const float4*)(xs_p);
      const float4 a1 = *(const float4*)(xs_p + 4);
      const float4 a2 = *(const float4*)(xs_p + 8);
      const float4 a3 = *(const float4*)(xs_p + 12);

      float d = a0.x * xd0.x + a0.y * xd0.y + a0.z * xd0.z + a0.w * xd0.w
              + a1.x * xd1.x + a1.y * xd1.y + a1.z * xd1.z + a1.w * xd1.w
              + a2.x * xd2.x + a2.y * xd2.y + a2.z * xd2.z + a2.w * xd2.w
              + a3.x * xd3.x + a3.y * xd3.y + a3.z * xd3.z + a3.w * xd3.w;
      d += __shfl_xor(d, 1);
      d += __shfl_xor(d, 2);
      d += __shfl_xor(d, 4);

      const float w = __expf(bi * isa * d);
      s += w;
      yv[0]  += w * a0.x; yv[1]  += w * a0.y; yv[2]  += w * a0.z; yv[3]  += w * a0.w;
      yv[4]  += w * a1.x; yv[5]  += w * a1.y; yv[6]  += w * a1.z; yv[7]  += w * a1.w;
      yv[8]  += w * a2.x; yv[9]  += w * a2.y; yv[10] += w * a2.z; yv[11] += w * a2.w;
      yv[12] += w * a3.x; yv[13] += w * a3.y; yv[14] += w * a3.z; yv[15] += w * a3.w;
    }

    // merge the 8 group-partials (groups differ in lane bits 3..5)
    s += __shfl_xor(s, 8);
    s += __shfl_xor(s, 16);
    s += __shfl_xor(s, 32);
#pragma unroll
    for (int k = 0; k < 16; ++k) {
      yv[k] += __shfl_xor(yv[k], 8);
      yv[k] += __shfl_xor(yv[k], 16);
      yv[k] += __shfl_xor(yv[k], 32);
    }
    if (end > beg) {
      const float r = coef / fmaxf(s, 1e-12f);
#pragma unroll
      for (int k = 0; k < 16; ++k) acc[k] += r * yv[k];
    }
  }

  if (inv_out) {                     // fused row-norm of the output row
    float ss = 0.f;
#pragma unroll
    for (int k = 0; k < 16; ++k) ss += acc[k] * acc[k];
    ss += __shfl_xor(ss, 1);
    ss += __shfl_xor(ss, 2);
    ss += __shfl_xor(ss, 4);
    if (lane == 0) inv_out[wid] = 1.0f / fmaxf(sqrtf(ss), 1e-12f);
  }

  if (grp == 0) {
    float* yp = y_out + (size_t)wid * DHID + sub * 16;
    *(float4*)(yp)      = make_float4(acc[0],  acc[1],  acc[2],  acc[3]);
    *(float4*)(yp + 4)  = make_float4(acc[4],  acc[5],  acc[6],  acc[7]);
    *(float4*)(yp + 8)  = make_float4(acc[8],  acc[9],  acc[10], acc[11]);
    *(float4*)(yp + 12) = make_float4(acc[12], acc[13], acc[14], acc[15]);
  }
}

// ---------------- launcher ----------------------------------------------------
extern "C" void kernel_launch(void* const* d_in, const int* in_sizes, int n_in,
                              void* d_out, int out_size, void* d_ws, size_t ws_size,
                              hipStream_t stream)
{
  const float* X          = (const float*)d_in[0];
  const int*   src1       = (const int*)d_in[1];
  const int*   dst1       = (const int*)d_in[2];
  const int*   src2       = (const int*)d_in[3];
  const int*   dst2       = (const int*)d_in[4];
  const float* order_attn = (const float*)d_in[5];
  const float* W1         = (const float*)d_in[6];
  const float* b1         = (const float*)d_in[7];
  const float* W2         = (const float*)d_in[8];
  const float* b2         = (const float*)d_in[9];
  const float* beta1      = (const float*)d_in[10];
  const float* beta2      = (const float*)d_in[11];
  float*       out        = (float*)d_out;

  char*  ws  = (char*)d_ws;
  size_t off = 0;
  auto alloc = [&](size_t bytes) -> void* {
    void* p = ws + off;
    off += (bytes + 255) & ~size_t(255);
    return p;
  };
  float* x1    = (float*)alloc((size_t)NNODES * DHID * 4);
  float* x2    = (float*)alloc((size_t)NNODES * DHID * 4);
  float* inv1  = (float*)alloc((size_t)NNODES * 4);
  float* inv2  = (float*)alloc((size_t)NNODES * 4);
  int*   rp1   = (int*)alloc((size_t)(NNODES + 1) * 4);
  int*   rp2   = (int*)alloc((size_t)(NNODES + 1) * 4);
  int*   col1  = (int*)alloc((size_t)NEDGES * 4);
  int*   col2  = (int*)alloc((size_t)NEDGES * 4);
  int*   H     = (int*)alloc((size_t)2 * NBK * PPART * 4);
  int*   btot  = (int*)alloc((size_t)2 * NBK * 4);
  int*   boffG = (int*)alloc((size_t)(2 * NBK + 1) * 4);
  // staging overlays x2: 2E*8 = 12.8 MB <= 25.6 MB, dead before agnn writes x2
  int2*  st    = (int2*)x2;
  float* x3    = x1;   // x1 dead after layer1 -> reuse

  const int WB = (NNODES + 3) / 4;   // 4 waves (nodes) per 256-thread block

  // CSR for both views (reused by both layers); no global atomics, segments
  // sorted in LDS -> fully deterministic across replays.
  hist_part_kernel<<<2 * PPART, 256, 0, stream>>>(dst1, dst2, H);
  scan_bucket_kernel<<<2 * NBK, 128, 0, stream>>>(H, btot);
  scan_btot_kernel<<<1, 1024, 0, stream>>>(btot, boffG);
  scatter_part_kernel<<<2 * PPART, 256, 0, stream>>>(src1, dst1, src2, dst2,
                                                     H, boffG, st);
  build_buckets_kernel<<<2 * NBK, 256, 0, stream>>>(st, boffG, rp1, rp2, col1, col2);

  fc1_kernel<<<NNODES / 16, 256, 0, stream>>>(X, W1, b1, x1, inv1);

  agnn_layer_kernel<<<WB, 256, 0, stream>>>(x1, inv1, rp1, col1, rp2, col2,
                                            beta1, order_attn, x2, inv2, NNODES);
  agnn_layer_kernel<<<WB, 256, 0, stream>>>(x2, inv2, rp1, col1, rp2, col2,
                                            beta2, order_attn, x3, nullptr, NNODES);

  fc2_kernel<<<NNODES / 8, 320, 0, stream>>>(x3, W2, b2, out);
}

// Round 8
// 417.322 us; speedup vs baseline: 1.0502x; 1.0502x over previous
//
#include <hip/hip_runtime.h>
#include <math.h>

#define NNODES 50000
#define NEDGES 800000
#define DIN    256
#define DHID   128
#define NCLS   40

#define BW    128                    // dst values per bucket
#define NBK   391                    // ceil(NNODES / BW)
#define CAP   6144                   // LDS col capacity per bucket (mean 2048, sd ~45)
#define PPART 128                    // partition blocks per view
#define CHUNK 6250                   // NEDGES / PPART

// ---------------- fc1: x1 = relu(X @ W1 + b1) + fused row-norm ---------------
__global__ __launch_bounds__(256) void fc1_kernel(
    const float* __restrict__ X, const float* __restrict__ W1,
    const float* __restrict__ b1, float* __restrict__ x1,
    float* __restrict__ inv1)
{
  __shared__ float Xs[16][DIN];      // 16 KB
  __shared__ float ssrow[16];
  const int tid   = threadIdx.x;
  const int node0 = blockIdx.x * 16;

  if (tid < 16) ssrow[tid] = 0.f;
  const float4* Xv  = (const float4*)(X + (size_t)node0 * DIN);
  float4*       Xsv = (float4*)(&Xs[0][0]);
#pragma unroll
  for (int t = 0; t < 4; ++t) Xsv[tid + t * 256] = Xv[tid + t * 256];
  __syncthreads();

  const int h  = tid & 127;
  const int tm = tid >> 7;           // 0..1 -> node groups of 8
  float acc[8];
#pragma unroll
  for (int r = 0; r < 8; ++r) acc[r] = 0.f;

  for (int k = 0; k < DIN; k += 4) {
    const float w0 = W1[(k + 0) * DHID + h];
    const float w1 = W1[(k + 1) * DHID + h];
    const float w2 = W1[(k + 2) * DHID + h];
    const float w3 = W1[(k + 3) * DHID + h];
#pragma unroll
    for (int r = 0; r < 8; ++r) {
      const float4 xv = *(const float4*)&Xs[tm * 8 + r][k];   // ds_read_b128 broadcast
      acc[r] += xv.x * w0 + xv.y * w1 + xv.z * w2 + xv.w * w3;
    }
  }
  const float bb   = b1[h];
  const int   lane = tid & 63;
#pragma unroll
  for (int r = 0; r < 8; ++r) {
    float v = acc[r] + bb;
    v = v > 0.f ? v : 0.f;
    x1[(size_t)(node0 + tm * 8 + r) * DHID + h] = v;
    float q = v * v;                 // fused norm: reduce over 128 cols (2 waves)
#pragma unroll
    for (int off = 32; off; off >>= 1) q += __shfl_xor(q, off);
    if (lane == 0) atomicAdd(&ssrow[tm * 8 + r], q);   // exactly 2 adds/row: commutative
  }
  __syncthreads();
  if (tid < 16) inv1[node0 + tid] = 1.0f / fmaxf(sqrtf(ssrow[tid]), 1e-12f);
}

// ---------------- fc2: out = x3 @ W2 + b2, 8 nodes/block (320 thr) -----------
__global__ __launch_bounds__(320) void fc2_kernel(
    const float* __restrict__ x3, const float* __restrict__ W2,
    const float* __restrict__ b2, float* __restrict__ out)
{
  __shared__ float Xs[8][DHID];      // 4 KB
  const int tid   = threadIdx.x;
  const int node0 = blockIdx.x * 8;
  for (int idx = tid; idx < 8 * DHID; idx += 320)
    Xs[idx >> 7][idx & 127] = x3[(size_t)node0 * DHID + idx];
  __syncthreads();

  const int ns = tid / NCLS;         // 0..7
  const int c  = tid - ns * NCLS;    // 0..39
  float acc = b2[c];
#pragma unroll 8
  for (int k = 0; k < DHID; ++k) acc += Xs[ns][k] * W2[k * NCLS + c];
  out[(size_t)(node0 + ns) * NCLS + c] = acc;
}

// ---------------- CSR build: deterministic two-pass multi-split --------------
// K1: per-(view,block) LDS histogram of a private edge chunk -> H[v][bkt][blk]
__global__ __launch_bounds__(256) void hist_part_kernel(
    const int* __restrict__ dst1, const int* __restrict__ dst2,
    int* __restrict__ H)
{
  const int bid = blockIdx.x;
  const int v   = bid >= PPART;
  const int p   = v ? bid - PPART : bid;
  const int* __restrict__ dst = v ? dst2 : dst1;

  __shared__ int hist[NBK];
  for (int i = threadIdx.x; i < NBK; i += 256) hist[i] = 0;
  __syncthreads();
  const int beg = p * CHUNK;
  const int end = (beg + CHUNK < NEDGES) ? beg + CHUNK : NEDGES;
  for (int j = beg + threadIdx.x; j < end; j += 256)
    atomicAdd(&hist[dst[j] >> 7], 1);
  __syncthreads();
  for (int i = threadIdx.x; i < NBK; i += 256)
    H[(v * NBK + i) * PPART + p] = hist[i];
}

// K2a: per-bucket exclusive scan of its 128 partition counts (in place) + total
__global__ __launch_bounds__(128) void scan_bucket_kernel(
    int* __restrict__ H, int* __restrict__ btot)
{
  const int b   = blockIdx.x;        // 0..2*NBK-1
  const int tid = threadIdx.x;
  __shared__ int sm[PPART];
  const int v = H[b * PPART + tid];
  sm[tid] = v;
  __syncthreads();
  for (int off = 1; off < PPART; off <<= 1) {
    int t = (tid >= off) ? sm[tid - off] : 0;
    __syncthreads();
    sm[tid] += t;
    __syncthreads();
  }
  H[b * PPART + tid] = sm[tid] - v;  // exclusive within bucket
  if (tid == PPART - 1) btot[b] = sm[tid];
}

// K2b: scan 2*NBK bucket totals -> boffG (global bucket bases)
__global__ __launch_bounds__(1024) void scan_btot_kernel(
    const int* __restrict__ btot, int* __restrict__ boffG)
{
  __shared__ int sm[1024];
  const int tid = threadIdx.x;
  const int v = (tid < 2 * NBK) ? btot[tid] : 0;
  sm[tid] = v;
  __syncthreads();
  for (int off = 1; off < 1024; off <<= 1) {
    int t = (tid >= off) ? sm[tid - off] : 0;
    __syncthreads();
    sm[tid] += t;
    __syncthreads();
  }
  if (tid < 2 * NBK) boffG[tid] = sm[tid] - v;
  if (tid == 0) boffG[2 * NBK] = 2 * NEDGES;
}

// K3: place edges at exact positions (LDS cursors only; writes cluster ~128B)
__global__ __launch_bounds__(256) void scatter_part_kernel(
    const int* __restrict__ src1, const int* __restrict__ dst1,
    const int* __restrict__ src2, const int* __restrict__ dst2,
    const int* __restrict__ H, const int* __restrict__ boffG,
    int2* __restrict__ st)
{
  const int bid = blockIdx.x;
  const int v   = bid >= PPART;
  const int p   = v ? bid - PPART : bid;
  const int* __restrict__ src = v ? src2 : src1;
  const int* __restrict__ dst = v ? dst2 : dst1;

  __shared__ int lcur[NBK];
  for (int i = threadIdx.x; i < NBK; i += 256)
    lcur[i] = boffG[v * NBK + i] + H[(v * NBK + i) * PPART + p];
  __syncthreads();
  const int beg = p * CHUNK;
  const int end = (beg + CHUNK < NEDGES) ? beg + CHUNK : NEDGES;
  for (int j = beg + threadIdx.x; j < end; j += 256) {
    const int s = src[j], d = dst[j];
    const int k = atomicAdd(&lcur[d >> 7], 1);
    st[k] = make_int2(s, d);
  }
}

// K4: per bucket: degrees -> rp, place srcs in LDS, sort segments (determinism),
//     coalesced col write.
__global__ __launch_bounds__(256) void build_buckets_kernel(
    const int2* __restrict__ st, const int* __restrict__ boffG,
    int* __restrict__ rp1, int* __restrict__ rp2,
    int* __restrict__ col1, int* __restrict__ col2)
{
  const int bid = blockIdx.x;
  const int v   = bid >= NBK;
  const int b   = v ? bid - NBK : bid;
  int* __restrict__ rp  = v ? rp2 : rp1;
  int* __restrict__ col = v ? col2 : col1;
  const int tid = threadIdx.x;

  const int off0G  = boffG[bid];
  const int cnt    = boffG[bid + 1] - off0G;
  const int off0   = off0G - v * NEDGES;    // view-local offset
  const int base_d = b * BW;
  const int nd     = (NNODES - base_d < BW) ? (NNODES - base_d) : BW;

  __shared__ int deg[BW];
  __shared__ int loff[BW + 1];
  __shared__ int cur[BW];
  __shared__ int lcol[CAP];

  if (tid < BW) deg[tid] = 0;
  __syncthreads();
  for (int j = tid; j < cnt; j += 256)
    atomicAdd(&deg[st[off0G + j].y - base_d], 1);
  __syncthreads();

  if (tid == 0) loff[0] = 0;
  if (tid < BW) loff[tid + 1] = deg[tid];
  __syncthreads();
  for (int off = 1; off < BW; off <<= 1) {
    int t = (tid < BW && tid + 1 >= off) ? loff[tid + 1 - off] : 0;
    __syncthreads();
    if (tid < BW && tid + 1 >= off) loff[tid + 1] += t;
    __syncthreads();
  }
  if (tid < nd) rp[base_d + tid] = off0 + loff[tid];
  if (tid == 0 && b == NBK - 1) rp[NNODES] = NEDGES;
  if (tid < BW) cur[tid] = loff[tid];
  __syncthreads();

  if (cnt <= CAP) {
    for (int j = tid; j < cnt; j += 256) {
      const int2 pr = st[off0G + j];
      const int k = atomicAdd(&cur[pr.y - base_d], 1);
      lcol[k] = pr.x;
    }
    __syncthreads();
    if (tid < nd) {                   // sort own segment ascending (in LDS)
      const int s0 = loff[tid], s1 = s0 + deg[tid];
      for (int a = s0 + 1; a < s1; ++a) {
        const int key = lcol[a];
        int c = a - 1;
        while (c >= s0 && lcol[c] > key) { lcol[c + 1] = lcol[c]; --c; }
        lcol[c + 1] = key;
      }
    }
    __syncthreads();
    for (int j = tid; j < cnt; j += 256) col[off0 + j] = lcol[j];
  } else {                            // overflow fallback (never for random data)
    for (int j = tid; j < cnt; j += 256) {
      const int2 pr = st[off0G + j];
      const int k = atomicAdd(&cur[pr.y - base_d], 1);
      col[off0 + k] = pr.x;
    }
    __syncthreads();
    if (tid < nd) {
      const int s0 = off0 + loff[tid], s1 = s0 + deg[tid];
      for (int a = s0 + 1; a < s1; ++a) {
        const int key = col[a];
        int c = a - 1;
        while (c >= s0 && col[c] > key) { col[c + 1] = col[c]; --c; }
        col[c + 1] = key;
      }
    }
  }
}

// ---------------- AGNN layer: both views fused in one round loop -------------
// 16-lane groups (4 edges/view in flight, 8 dims/lane); both views' gather
// chains overlap every round -> 8 outstanding edge gathers/wave at R6's
// register geometry. Branchless: exhausted views load a clamped valid index
// and contribute w=0. col prefetched one round ahead (drops the leading link
// of the col->x dependency chain). softmax shift-invariance: w = exp(e).
__global__ __launch_bounds__(256) void agnn_layer_kernel(
    const float* __restrict__ x, const float* __restrict__ inv,
    const int* __restrict__ rp1, const int* __restrict__ col1,
    const int* __restrict__ rp2, const int* __restrict__ col2,
    const float* __restrict__ beta_p, const float* __restrict__ order_attn,
    float* __restrict__ y_out, float* __restrict__ inv_out, int n)
{
  const int wid  = (blockIdx.x * blockDim.x + threadIdx.x) >> 6;
  if (wid >= n) return;
  const int lane = threadIdx.x & 63;
  const int grp  = lane >> 4;        // 0..3  : edge slot within each view
  const int sub  = lane & 15;        // 0..15 : 8 dims each -> 128 dims

  const float beta = beta_p[0];
  const float bi   = beta * inv[wid];

  const float* xd_p = x + (size_t)wid * DHID + sub * 8;
  const float4 xd0 = *(const float4*)(xd_p);
  const float4 xd1 = *(const float4*)(xd_p + 4);

  const int beg1 = rp1[wid], end1 = rp1[wid + 1];
  const int beg2 = rp2[wid], end2 = rp2[wid + 1];

  float s1 = 0.f, s2 = 0.f;
  float y1[8], y2[8];
#pragma unroll
  for (int k = 0; k < 8; ++k) { y1[k] = 0.f; y2[k] = 0.f; }

  int j1 = beg1 + grp, j2 = beg2 + grp;
  // prefetch first col of each view (clamped to a valid index)
  int sa1 = col1[j1 < end1 ? j1 : 0];
  int sa2 = col2[j2 < end2 ? j2 : 0];

  while (j1 < end1 || j2 < end2) {
    const bool p1 = j1 < end1;
    const bool p2 = j2 < end2;
    const int  c1 = sa1, c2 = sa2;

    // issue this round's inv + x gathers for BOTH views up front
    const float isa1 = inv[c1];
    const float isa2 = inv[c2];
    const float* xp1 = x + (size_t)c1 * DHID + sub * 8;
    const float* xp2 = x + (size_t)c2 * DHID + sub * 8;
    const float4 a0 = *(const float4*)(xp1);
    const float4 a1 = *(const float4*)(xp1 + 4);
    const float4 b0 = *(const float4*)(xp2);
    const float4 b1 = *(const float4*)(xp2 + 4);

    // prefetch next round's cols (overlaps with this round's compute)
    const int nj1 = j1 + 4, nj2 = j2 + 4;
    sa1 = col1[nj1 < end1 ? nj1 : 0];
    sa2 = col2[nj2 < end2 ? nj2 : 0];

    float d1 = a0.x * xd0.x + a0.y * xd0.y + a0.z * xd0.z + a0.w * xd0.w
             + a1.x * xd1.x + a1.y * xd1.y + a1.z * xd1.z + a1.w * xd1.w;
    float d2 = b0.x * xd0.x + b0.y * xd0.y + b0.z * xd0.z + b0.w * xd0.w
             + b1.x * xd1.x + b1.y * xd1.y + b1.z * xd1.z + b1.w * xd1.w;
#pragma unroll
    for (int off = 1; off <= 8; off <<= 1) {
      d1 += __shfl_xor(d1, off);
      d2 += __shfl_xor(d2, off);
    }

    const float w1 = p1 ? __expf(bi * isa1 * d1) : 0.f;
    const float w2 = p2 ? __expf(bi * isa2 * d2) : 0.f;
    s1 += w1; s2 += w2;
    y1[0] += w1 * a0.x; y1[1] += w1 * a0.y; y1[2] += w1 * a0.z; y1[3] += w1 * a0.w;
    y1[4] += w1 * a1.x; y1[5] += w1 * a1.y; y1[6] += w1 * a1.z; y1[7] += w1 * a1.w;
    y2[0] += w2 * b0.x; y2[1] += w2 * b0.y; y2[2] += w2 * b0.z; y2[3] += w2 * b0.w;
    y2[4] += w2 * b1.x; y2[5] += w2 * b1.y; y2[6] += w2 * b1.z; y2[7] += w2 * b1.w;

    j1 = nj1; j2 = nj2;
  }

  // merge the 4 group-partials (groups differ in lane bits 4..5)
  s1 += __shfl_xor(s1, 16); s1 += __shfl_xor(s1, 32);
  s2 += __shfl_xor(s2, 16); s2 += __shfl_xor(s2, 32);
#pragma unroll
  for (int k = 0; k < 8; ++k) {
    y1[k] += __shfl_xor(y1[k], 16); y1[k] += __shfl_xor(y1[k], 32);
    y2[k] += __shfl_xor(y2[k], 16); y2[k] += __shfl_xor(y2[k], 32);
  }

  const float r1 = (end1 > beg1) ? order_attn[0] / fmaxf(s1, 1e-12f) : 0.f;
  const float r2 = (end2 > beg2) ? order_attn[1] / fmaxf(s2, 1e-12f) : 0.f;
  float acc[8];
#pragma unroll
  for (int k = 0; k < 8; ++k) acc[k] = r1 * y1[k] + r2 * y2[k];

  if (inv_out) {                     // fused row-norm of the output row
    float ss = 0.f;
#pragma unroll
    for (int k = 0; k < 8; ++k) ss += acc[k] * acc[k];
    ss += __shfl_xor(ss, 1);
    ss += __shfl_xor(ss, 2);
    ss += __shfl_xor(ss, 4);
    ss += __shfl_xor(ss, 8);
    if (lane == 0) inv_out[wid] = 1.0f / fmaxf(sqrtf(ss), 1e-12f);
  }

  if (grp == 0) {
    float* yp = y_out + (size_t)wid * DHID + sub * 8;
    *(float4*)(yp)     = make_float4(acc[0], acc[1], acc[2], acc[3]);
    *(float4*)(yp + 4) = make_float4(acc[4], acc[5], acc[6], acc[7]);
  }
}

// ---------------- launcher ----------------------------------------------------
extern "C" void kernel_launch(void* const* d_in, const int* in_sizes, int n_in,
                              void* d_out, int out_size, void* d_ws, size_t ws_size,
                              hipStream_t stream)
{
  const float* X          = (const float*)d_in[0];
  const int*   src1       = (const int*)d_in[1];
  const int*   dst1       = (const int*)d_in[2];
  const int*   src2       = (const int*)d_in[3];
  const int*   dst2       = (const int*)d_in[4];
  const float* order_attn = (const float*)d_in[5];
  const float* W1         = (const float*)d_in[6];
  const float* b1         = (const float*)d_in[7];
  const float* W2         = (const float*)d_in[8];
  const float* b2         = (const float*)d_in[9];
  const float* beta1      = (const float*)d_in[10];
  const float* beta2      = (const float*)d_in[11];
  float*       out        = (float*)d_out;

  char*  ws  = (char*)d_ws;
  size_t off = 0;
  auto alloc = [&](size_t bytes) -> void* {
    void* p = ws + off;
    off += (bytes + 255) & ~size_t(255);
    return p;
  };
  float* x1    = (float*)alloc((size_t)NNODES * DHID * 4);
  float* x2    = (float*)alloc((size_t)NNODES * DHID * 4);
  float* inv1  = (float*)alloc((size_t)NNODES * 4);
  float* inv2  = (float*)alloc((size_t)NNODES * 4);
  int*   rp1   = (int*)alloc((size_t)(NNODES + 1) * 4);
  int*   rp2   = (int*)alloc((size_t)(NNODES + 1) * 4);
  int*   col1  = (int*)alloc((size_t)NEDGES * 4);
  int*   col2  = (int*)alloc((size_t)NEDGES * 4);
  int*   H     = (int*)alloc((size_t)2 * NBK * PPART * 4);
  int*   btot  = (int*)alloc((size_t)2 * NBK * 4);
  int*   boffG = (int*)alloc((size_t)(2 * NBK + 1) * 4);
  // staging overlays x2: 2E*8 = 12.8 MB <= 25.6 MB, dead before agnn writes x2
  int2*  st    = (int2*)x2;
  float* x3    = x1;   // x1 dead after layer1 -> reuse

  const int WB = (NNODES + 3) / 4;   // 4 waves (nodes) per 256-thread block

  // CSR for both views (reused by both layers); no global atomics, segments
  // sorted in LDS -> fully deterministic across replays.
  hist_part_kernel<<<2 * PPART, 256, 0, stream>>>(dst1, dst2, H);
  scan_bucket_kernel<<<2 * NBK, 128, 0, stream>>>(H, btot);
  scan_btot_kernel<<<1, 1024, 0, stream>>>(btot, boffG);
  scatter_part_kernel<<<2 * PPART, 256, 0, stream>>>(src1, dst1, src2, dst2,
                                                     H, boffG, st);
  build_buckets_kernel<<<2 * NBK, 256, 0, stream>>>(st, boffG, rp1, rp2, col1, col2);

  fc1_kernel<<<NNODES / 16, 256, 0, stream>>>(X, W1, b1, x1, inv1);

  agnn_layer_kernel<<<WB, 256, 0, stream>>>(x1, inv1, rp1, col1, rp2, col2,
                                            beta1, order_attn, x2, inv2, NNODES);
  agnn_layer_kernel<<<WB, 256, 0, stream>>>(x2, inv2, rp1, col1, rp2, col2,
                                            beta2, order_attn, x3, nullptr, NNODES);

  fc2_kernel<<<NNODES / 8, 320, 0, stream>>>(x3, W2, b2, out);
}

// Round 9
// 336.554 us; speedup vs baseline: 1.3022x; 1.2400x over previous
//
#include <hip/hip_runtime.h>
#include <hip/hip_fp16.h>
#include <math.h>

#define NNODES 50000
#define NEDGES 800000
#define DIN    256
#define DHID   128
#define NCLS   40

#define BW    128                    // dst values per bucket
#define NBK   391                    // ceil(NNODES / BW)
#define CAP   6144                   // LDS col capacity per bucket (mean 2048, sd ~45)
#define PPART 128                    // partition blocks per view
#define CHUNK 6250                   // NEDGES / PPART

union HF8 { float4 f; __half2 h2[4]; };   // 8 fp16 <-> 16 B

// ---------------- fc1: x1h = fp16(relu(X @ W1 + b1)) + fused row-norm --------
__global__ __launch_bounds__(256) void fc1_kernel(
    const float* __restrict__ X, const float* __restrict__ W1,
    const float* __restrict__ b1, __half* __restrict__ x1h,
    float* __restrict__ inv1)
{
  __shared__ float Xs[16][DIN];      // 16 KB
  __shared__ float ssrow[16];
  const int tid   = threadIdx.x;
  const int node0 = blockIdx.x * 16;

  if (tid < 16) ssrow[tid] = 0.f;
  const float4* Xv  = (const float4*)(X + (size_t)node0 * DIN);
  float4*       Xsv = (float4*)(&Xs[0][0]);
#pragma unroll
  for (int t = 0; t < 4; ++t) Xsv[tid + t * 256] = Xv[tid + t * 256];
  __syncthreads();

  const int h  = tid & 127;
  const int tm = tid >> 7;           // 0..1 -> node groups of 8
  float acc[8];
#pragma unroll
  for (int r = 0; r < 8; ++r) acc[r] = 0.f;

  for (int k = 0; k < DIN; k += 4) {
    const float w0 = W1[(k + 0) * DHID + h];
    const float w1 = W1[(k + 1) * DHID + h];
    const float w2 = W1[(k + 2) * DHID + h];
    const float w3 = W1[(k + 3) * DHID + h];
#pragma unroll
    for (int r = 0; r < 8; ++r) {
      const float4 xv = *(const float4*)&Xs[tm * 8 + r][k];   // ds_read_b128 broadcast
      acc[r] += xv.x * w0 + xv.y * w1 + xv.z * w2 + xv.w * w3;
    }
  }
  const float bb   = b1[h];
  const int   lane = tid & 63;
#pragma unroll
  for (int r = 0; r < 8; ++r) {
    float v = acc[r] + bb;
    v = v > 0.f ? v : 0.f;
    x1h[(size_t)(node0 + tm * 8 + r) * DHID + h] = __float2half(v);
    float q = v * v;                 // norm from fp32 pre-rounding values
#pragma unroll
    for (int off = 32; off; off >>= 1) q += __shfl_xor(q, off);
    if (lane == 0) atomicAdd(&ssrow[tm * 8 + r], q);   // exactly 2 adds/row: commutative
  }
  __syncthreads();
  if (tid < 16) inv1[node0 + tid] = 1.0f / fmaxf(sqrtf(ssrow[tid]), 1e-12f);
}

// ---------------- fc2: out = x3 @ W2 + b2, 8 nodes/block (320 thr) -----------
__global__ __launch_bounds__(320) void fc2_kernel(
    const float* __restrict__ x3, const float* __restrict__ W2,
    const float* __restrict__ b2, float* __restrict__ out)
{
  __shared__ float Xs[8][DHID];      // 4 KB
  const int tid   = threadIdx.x;
  const int node0 = blockIdx.x * 8;
  for (int idx = tid; idx < 8 * DHID; idx += 320)
    Xs[idx >> 7][idx & 127] = x3[(size_t)node0 * DHID + idx];
  __syncthreads();

  const int ns = tid / NCLS;         // 0..7
  const int c  = tid - ns * NCLS;    // 0..39
  float acc = b2[c];
#pragma unroll 8
  for (int k = 0; k < DHID; ++k) acc += Xs[ns][k] * W2[k * NCLS + c];
  out[(size_t)(node0 + ns) * NCLS + c] = acc;
}

// ---------------- CSR build: deterministic two-pass multi-split --------------
// K1: per-(view,block) LDS histogram of a private edge chunk -> H[v][bkt][blk]
__global__ __launch_bounds__(256) void hist_part_kernel(
    const int* __restrict__ dst1, const int* __restrict__ dst2,
    int* __restrict__ H)
{
  const int bid = blockIdx.x;
  const int v   = bid >= PPART;
  const int p   = v ? bid - PPART : bid;
  const int* __restrict__ dst = v ? dst2 : dst1;

  __shared__ int hist[NBK];
  for (int i = threadIdx.x; i < NBK; i += 256) hist[i] = 0;
  __syncthreads();
  const int beg = p * CHUNK;
  const int end = (beg + CHUNK < NEDGES) ? beg + CHUNK : NEDGES;
  for (int j = beg + threadIdx.x; j < end; j += 256)
    atomicAdd(&hist[dst[j] >> 7], 1);
  __syncthreads();
  for (int i = threadIdx.x; i < NBK; i += 256)
    H[(v * NBK + i) * PPART + p] = hist[i];
}

// K2a: per-bucket exclusive scan of its 128 partition counts (in place) + total
__global__ __launch_bounds__(128) void scan_bucket_kernel(
    int* __restrict__ H, int* __restrict__ btot)
{
  const int b   = blockIdx.x;        // 0..2*NBK-1
  const int tid = threadIdx.x;
  __shared__ int sm[PPART];
  const int v = H[b * PPART + tid];
  sm[tid] = v;
  __syncthreads();
  for (int off = 1; off < PPART; off <<= 1) {
    int t = (tid >= off) ? sm[tid - off] : 0;
    __syncthreads();
    sm[tid] += t;
    __syncthreads();
  }
  H[b * PPART + tid] = sm[tid] - v;  // exclusive within bucket
  if (tid == PPART - 1) btot[b] = sm[tid];
}

// K2b: scan 2*NBK bucket totals -> boffG (global bucket bases)
__global__ __launch_bounds__(1024) void scan_btot_kernel(
    const int* __restrict__ btot, int* __restrict__ boffG)
{
  __shared__ int sm[1024];
  const int tid = threadIdx.x;
  const int v = (tid < 2 * NBK) ? btot[tid] : 0;
  sm[tid] = v;
  __syncthreads();
  for (int off = 1; off < 1024; off <<= 1) {
    int t = (tid >= off) ? sm[tid - off] : 0;
    __syncthreads();
    sm[tid] += t;
    __syncthreads();
  }
  if (tid < 2 * NBK) boffG[tid] = sm[tid] - v;
  if (tid == 0) boffG[2 * NBK] = 2 * NEDGES;
}

// K3: place edges at exact positions (LDS cursors only; writes cluster ~128B)
__global__ __launch_bounds__(256) void scatter_part_kernel(
    const int* __restrict__ src1, const int* __restrict__ dst1,
    const int* __restrict__ src2, const int* __restrict__ dst2,
    const int* __restrict__ H, const int* __restrict__ boffG,
    int2* __restrict__ st)
{
  const int bid = blockIdx.x;
  const int v   = bid >= PPART;
  const int p   = v ? bid - PPART : bid;
  const int* __restrict__ src = v ? src2 : src1;
  const int* __restrict__ dst = v ? dst2 : dst1;

  __shared__ int lcur[NBK];
  for (int i = threadIdx.x; i < NBK; i += 256)
    lcur[i] = boffG[v * NBK + i] + H[(v * NBK + i) * PPART + p];
  __syncthreads();
  const int beg = p * CHUNK;
  const int end = (beg + CHUNK < NEDGES) ? beg + CHUNK : NEDGES;
  for (int j = beg + threadIdx.x; j < end; j += 256) {
    const int s = src[j], d = dst[j];
    const int k = atomicAdd(&lcur[d >> 7], 1);
    st[k] = make_int2(s, d);
  }
}

// K4: per bucket: degrees -> rp, place srcs in LDS, sort segments (determinism),
//     coalesced col write.
__global__ __launch_bounds__(256) void build_buckets_kernel(
    const int2* __restrict__ st, const int* __restrict__ boffG,
    int* __restrict__ rp1, int* __restrict__ rp2,
    int* __restrict__ col1, int* __restrict__ col2)
{
  const int bid = blockIdx.x;
  const int v   = bid >= NBK;
  const int b   = v ? bid - NBK : bid;
  int* __restrict__ rp  = v ? rp2 : rp1;
  int* __restrict__ col = v ? col2 : col1;
  const int tid = threadIdx.x;

  const int off0G  = boffG[bid];
  const int cnt    = boffG[bid + 1] - off0G;
  const int off0   = off0G - v * NEDGES;    // view-local offset
  const int base_d = b * BW;
  const int nd     = (NNODES - base_d < BW) ? (NNODES - base_d) : BW;

  __shared__ int deg[BW];
  __shared__ int loff[BW + 1];
  __shared__ int cur[BW];
  __shared__ int lcol[CAP];

  if (tid < BW) deg[tid] = 0;
  __syncthreads();
  for (int j = tid; j < cnt; j += 256)
    atomicAdd(&deg[st[off0G + j].y - base_d], 1);
  __syncthreads();

  if (tid == 0) loff[0] = 0;
  if (tid < BW) loff[tid + 1] = deg[tid];
  __syncthreads();
  for (int off = 1; off < BW; off <<= 1) {
    int t = (tid < BW && tid + 1 >= off) ? loff[tid + 1 - off] : 0;
    __syncthreads();
    if (tid < BW && tid + 1 >= off) loff[tid + 1] += t;
    __syncthreads();
  }
  if (tid < nd) rp[base_d + tid] = off0 + loff[tid];
  if (tid == 0 && b == NBK - 1) rp[NNODES] = NEDGES;
  if (tid < BW) cur[tid] = loff[tid];
  __syncthreads();

  if (cnt <= CAP) {
    for (int j = tid; j < cnt; j += 256) {
      const int2 pr = st[off0G + j];
      const int k = atomicAdd(&cur[pr.y - base_d], 1);
      lcol[k] = pr.x;
    }
    __syncthreads();
    if (tid < nd) {                   // sort own segment ascending (in LDS)
      const int s0 = loff[tid], s1 = s0 + deg[tid];
      for (int a = s0 + 1; a < s1; ++a) {
        const int key = lcol[a];
        int c = a - 1;
        while (c >= s0 && lcol[c] > key) { lcol[c + 1] = lcol[c]; --c; }
        lcol[c + 1] = key;
      }
    }
    __syncthreads();
    for (int j = tid; j < cnt; j += 256) col[off0 + j] = lcol[j];
  } else {                            // overflow fallback (never for random data)
    for (int j = tid; j < cnt; j += 256) {
      const int2 pr = st[off0G + j];
      const int k = atomicAdd(&cur[pr.y - base_d], 1);
      col[off0 + k] = pr.x;
    }
    __syncthreads();
    if (tid < nd) {
      const int s0 = off0 + loff[tid], s1 = s0 + deg[tid];
      for (int a = s0 + 1; a < s1; ++a) {
        const int key = col[a];
        int c = a - 1;
        while (c >= s0 && col[c] > key) { col[c + 1] = col[c]; --c; }
        col[c + 1] = key;
      }
    }
  }
}

// ---------------- AGNN layer: fused views, fp16 feature gathers --------------
// 16-lane groups (4 edges/view in flight, 8 dims/lane, one 16 B fp16 load per
// view per lane). Dots/aggregation accumulate fp32. Branchless round loop with
// col prefetch. softmax shift-invariance: w = exp(e) directly.
// Outputs: yh_out (fp16, for next layer) and/or y32_out (fp32, for fc2),
// plus optional fused row-norm inv_out (from fp32 pre-rounding values).
__global__ __launch_bounds__(256) void agnn_layer_kernel(
    const __half* __restrict__ xh, const float* __restrict__ inv,
    const int* __restrict__ rp1, const int* __restrict__ col1,
    const int* __restrict__ rp2, const int* __restrict__ col2,
    const float* __restrict__ beta_p, const float* __restrict__ order_attn,
    __half* __restrict__ yh_out, float* __restrict__ inv_out,
    float* __restrict__ y32_out, int n)
{
  const int wid  = (blockIdx.x * blockDim.x + threadIdx.x) >> 6;
  if (wid >= n) return;
  const int lane = threadIdx.x & 63;
  const int grp  = lane >> 4;        // 0..3  : edge slot within each view
  const int sub  = lane & 15;        // 0..15 : 8 dims each -> 128 dims

  const float beta = beta_p[0];
  const float bi   = beta * inv[wid];

  HF8 ud; ud.f = *(const float4*)(xh + (size_t)wid * DHID + sub * 8);
  float xd[8];
#pragma unroll
  for (int i = 0; i < 4; ++i) {
    const float2 t = __half22float2(ud.h2[i]);
    xd[2 * i] = t.x; xd[2 * i + 1] = t.y;
  }

  const int beg1 = rp1[wid], end1 = rp1[wid + 1];
  const int beg2 = rp2[wid], end2 = rp2[wid + 1];

  float s1 = 0.f, s2 = 0.f;
  float y1[8], y2[8];
#pragma unroll
  for (int k = 0; k < 8; ++k) { y1[k] = 0.f; y2[k] = 0.f; }

  int j1 = beg1 + grp, j2 = beg2 + grp;
  int sa1 = col1[j1 < end1 ? j1 : 0];
  int sa2 = col2[j2 < end2 ? j2 : 0];

  while (j1 < end1 || j2 < end2) {
    const bool p1 = j1 < end1;
    const bool p2 = j2 < end2;
    const int  c1 = sa1, c2 = sa2;

    // issue this round's inv + x gathers for BOTH views up front
    const float isa1 = inv[c1];
    const float isa2 = inv[c2];
    HF8 u1; u1.f = *(const float4*)(xh + (size_t)c1 * DHID + sub * 8);
    HF8 u2; u2.f = *(const float4*)(xh + (size_t)c2 * DHID + sub * 8);

    // prefetch next round's cols (overlaps with this round's compute)
    const int nj1 = j1 + 4, nj2 = j2 + 4;
    sa1 = col1[nj1 < end1 ? nj1 : 0];
    sa2 = col2[nj2 < end2 ? nj2 : 0];

    float av[8], bv[8];
#pragma unroll
    for (int i = 0; i < 4; ++i) {
      const float2 ta = __half22float2(u1.h2[i]);
      const float2 tb = __half22float2(u2.h2[i]);
      av[2 * i] = ta.x; av[2 * i + 1] = ta.y;
      bv[2 * i] = tb.x; bv[2 * i + 1] = tb.y;
    }

    float d1 = 0.f, d2 = 0.f;
#pragma unroll
    for (int k = 0; k < 8; ++k) { d1 += av[k] * xd[k]; d2 += bv[k] * xd[k]; }
#pragma unroll
    for (int off = 1; off <= 8; off <<= 1) {
      d1 += __shfl_xor(d1, off);
      d2 += __shfl_xor(d2, off);
    }

    const float w1 = p1 ? __expf(bi * isa1 * d1) : 0.f;
    const float w2 = p2 ? __expf(bi * isa2 * d2) : 0.f;
    s1 += w1; s2 += w2;
#pragma unroll
    for (int k = 0; k < 8; ++k) {
      y1[k] += w1 * av[k];
      y2[k] += w2 * bv[k];
    }

    j1 = nj1; j2 = nj2;
  }

  // merge the 4 group-partials (groups differ in lane bits 4..5)
  s1 += __shfl_xor(s1, 16); s1 += __shfl_xor(s1, 32);
  s2 += __shfl_xor(s2, 16); s2 += __shfl_xor(s2, 32);
#pragma unroll
  for (int k = 0; k < 8; ++k) {
    y1[k] += __shfl_xor(y1[k], 16); y1[k] += __shfl_xor(y1[k], 32);
    y2[k] += __shfl_xor(y2[k], 16); y2[k] += __shfl_xor(y2[k], 32);
  }

  const float r1 = (end1 > beg1) ? order_attn[0] / fmaxf(s1, 1e-12f) : 0.f;
  const float r2 = (end2 > beg2) ? order_attn[1] / fmaxf(s2, 1e-12f) : 0.f;
  float acc[8];
#pragma unroll
  for (int k = 0; k < 8; ++k) acc[k] = r1 * y1[k] + r2 * y2[k];

  if (inv_out) {                     // fused row-norm (fp32, pre-rounding)
    float ss = 0.f;
#pragma unroll
    for (int k = 0; k < 8; ++k) ss += acc[k] * acc[k];
    ss += __shfl_xor(ss, 1);
    ss += __shfl_xor(ss, 2);
    ss += __shfl_xor(ss, 4);
    ss += __shfl_xor(ss, 8);
    if (lane == 0) inv_out[wid] = 1.0f / fmaxf(sqrtf(ss), 1e-12f);
  }

  if (grp == 0) {
    if (yh_out) {
      HF8 o;
      o.h2[0] = __floats2half2_rn(acc[0], acc[1]);
      o.h2[1] = __floats2half2_rn(acc[2], acc[3]);
      o.h2[2] = __floats2half2_rn(acc[4], acc[5]);
      o.h2[3] = __floats2half2_rn(acc[6], acc[7]);
      *(float4*)(yh_out + (size_t)wid * DHID + sub * 8) = o.f;
    }
    if (y32_out) {
      float* yp = y32_out + (size_t)wid * DHID + sub * 8;
      *(float4*)(yp)     = make_float4(acc[0], acc[1], acc[2], acc[3]);
      *(float4*)(yp + 4) = make_float4(acc[4], acc[5], acc[6], acc[7]);
    }
  }
}

// ---------------- launcher ----------------------------------------------------
extern "C" void kernel_launch(void* const* d_in, const int* in_sizes, int n_in,
                              void* d_out, int out_size, void* d_ws, size_t ws_size,
                              hipStream_t stream)
{
  const float* X          = (const float*)d_in[0];
  const int*   src1       = (const int*)d_in[1];
  const int*   dst1       = (const int*)d_in[2];
  const int*   src2       = (const int*)d_in[3];
  const int*   dst2       = (const int*)d_in[4];
  const float* order_attn = (const float*)d_in[5];
  const float* W1         = (const float*)d_in[6];
  const float* b1         = (const float*)d_in[7];
  const float* W2         = (const float*)d_in[8];
  const float* b2         = (const float*)d_in[9];
  const float* beta1      = (const float*)d_in[10];
  const float* beta2      = (const float*)d_in[11];
  float*       out        = (float*)d_out;

  char*  ws  = (char*)d_ws;
  size_t off = 0;
  auto alloc = [&](size_t bytes) -> void* {
    void* p = ws + off;
    off += (bytes + 255) & ~size_t(255);
    return p;
  };
  __half* x1h  = (__half*)alloc((size_t)NNODES * DHID * 2);
  __half* x2h  = (__half*)alloc((size_t)NNODES * DHID * 2);
  float*  x3   = (float*)alloc((size_t)NNODES * DHID * 4);
  float*  inv1 = (float*)alloc((size_t)NNODES * 4);
  float*  inv2 = (float*)alloc((size_t)NNODES * 4);
  int*    rp1  = (int*)alloc((size_t)(NNODES + 1) * 4);
  int*    rp2  = (int*)alloc((size_t)(NNODES + 1) * 4);
  int*    col1 = (int*)alloc((size_t)NEDGES * 4);
  int*    col2 = (int*)alloc((size_t)NEDGES * 4);
  int*    H    = (int*)alloc((size_t)2 * NBK * PPART * 4);
  int*    btot = (int*)alloc((size_t)2 * NBK * 4);
  int*    boffG= (int*)alloc((size_t)(2 * NBK + 1) * 4);
  // staging overlays x3 (12.8 MB <= 25.6 MB): x3 written only by layer2,
  // after build_buckets has consumed st.
  int2*   st   = (int2*)x3;

  const int WB = (NNODES + 3) / 4;   // 4 waves (nodes) per 256-thread block

  // CSR for both views (reused by both layers); no global atomics, segments
  // sorted in LDS -> fully deterministic across replays.
  hist_part_kernel<<<2 * PPART, 256, 0, stream>>>(dst1, dst2, H);
  scan_bucket_kernel<<<2 * NBK, 128, 0, stream>>>(H, btot);
  scan_btot_kernel<<<1, 1024, 0, stream>>>(btot, boffG);
  scatter_part_kernel<<<2 * PPART, 256, 0, stream>>>(src1, dst1, src2, dst2,
                                                     H, boffG, st);
  build_buckets_kernel<<<2 * NBK, 256, 0, stream>>>(st, boffG, rp1, rp2, col1, col2);

  fc1_kernel<<<NNODES / 16, 256, 0, stream>>>(X, W1, b1, x1h, inv1);

  agnn_layer_kernel<<<WB, 256, 0, stream>>>(x1h, inv1, rp1, col1, rp2, col2,
                                            beta1, order_attn,
                                            x2h, inv2, nullptr, NNODES);
  agnn_layer_kernel<<<WB, 256, 0, stream>>>(x2h, inv2, rp1, col1, rp2, col2,
                                            beta2, order_attn,
                                            nullptr, nullptr, x3, NNODES);

  fc2_kernel<<<NNODES / 8, 320, 0, stream>>>(x3, W2, b2, out);
}

// Round 10
// 303.985 us; speedup vs baseline: 1.4418x; 1.1071x over previous
//
#include <hip/hip_runtime.h>
#include <hip/hip_fp16.h>
#include <math.h>

#define NNODES 50000
#define NEDGES 800000
#define DIN    256
#define DHID   128
#define NCLS   40

#define BW    128                    // dst values per bucket
#define NBK   391                    // ceil(NNODES / BW)
#define CAP   6144                   // LDS col capacity per bucket (mean 2048, sd ~45)
#define PPART 128                    // partition blocks per view
#define CHUNK 6250                   // NEDGES / PPART

union HF8 { float4 f; __half2 h2[4]; };   // 8 fp16 <-> 16 B
union HF4 { float2 f; __half2 h2[2]; };   // 4 fp16 <-> 8 B

// ---------------- fc1: register-blocked GEMM + fused relu/fp16/row-norm ------
// 64 nodes x 128 cols per 256-thread block; thread = 4m x 8n outer product.
__global__ __launch_bounds__(256) void fc1_kernel(
    const float* __restrict__ X, const float* __restrict__ W1,
    const float* __restrict__ b1, __half* __restrict__ x1h,
    float* __restrict__ inv1)
{
  __shared__ float As[64][65];       // X^T tile [k][m], padded
  __shared__ float Bs[64][132];      // W1 tile [k][n], padded
  const int tid   = threadIdx.x;
  const int node0 = blockIdx.x * 64;
  const int tx    = tid & 15;        // n-groups: cols {tx*4..+3} u {64+tx*4..+3}
  const int ty    = tid >> 4;        // m-group: rows ty*4..+3

  const int ml   = tid >> 2;         // 0..63 : staging row
  const int kq   = tid & 3;
  const int mrow = (node0 + ml < NNODES) ? node0 + ml : NNODES - 1;  // clamp

  float acc[4][8];
#pragma unroll
  for (int i = 0; i < 4; ++i)
#pragma unroll
    for (int j = 0; j < 8; ++j) acc[i][j] = 0.f;

  for (int kt = 0; kt < 4; ++kt) {
    const int k0 = kt * 64;
    // stage A (X^T): 4 float4 per thread, scalar transpose into As[k][m]
#pragma unroll
    for (int q = 0; q < 4; ++q) {
      const int kk = kq * 16 + q * 4;
      const float4 v = *(const float4*)(X + (size_t)mrow * DIN + k0 + kk);
      As[kk + 0][ml] = v.x; As[kk + 1][ml] = v.y;
      As[kk + 2][ml] = v.z; As[kk + 3][ml] = v.w;
    }
    // stage B (W1): 8 float4 per thread, coalesced
#pragma unroll
    for (int q = 0; q < 8; ++q) {
      const int flat = q * 1024 + tid * 4;
      const int kk = flat >> 7, nn = flat & 127;
      *(float4*)&Bs[kk][nn] = *(const float4*)(W1 + (size_t)(k0 + kk) * DHID + nn);
    }
    __syncthreads();

#pragma unroll 4
    for (int k = 0; k < 64; ++k) {
      const float4 a  = *(const float4*)&As[k][ty * 4];
      const float4 b0 = *(const float4*)&Bs[k][tx * 4];
      const float4 b1v= *(const float4*)&Bs[k][64 + tx * 4];
      const float av[4] = {a.x, a.y, a.z, a.w};
      const float bv[8] = {b0.x, b0.y, b0.z, b0.w, b1v.x, b1v.y, b1v.z, b1v.w};
#pragma unroll
      for (int i = 0; i < 4; ++i)
#pragma unroll
        for (int j = 0; j < 8; ++j) acc[i][j] += av[i] * bv[j];
    }
    __syncthreads();
  }

  // epilogue: bias + relu, fp16 store, fused row-norm (reduce over tx lanes)
  const float4 bb0 = *(const float4*)(b1 + tx * 4);
  const float4 bb1 = *(const float4*)(b1 + 64 + tx * 4);
  const float bias[8] = {bb0.x, bb0.y, bb0.z, bb0.w, bb1.x, bb1.y, bb1.z, bb1.w};

#pragma unroll
  for (int i = 0; i < 4; ++i) {
    const int row = node0 + ty * 4 + i;
    float v[8];
    float q = 0.f;
#pragma unroll
    for (int j = 0; j < 8; ++j) {
      float t = acc[i][j] + bias[j];
      t = t > 0.f ? t : 0.f;
      v[j] = t;
      q += t * t;
    }
    // row-sum over the 16 tx lanes (lane bits 0..3)
    q += __shfl_xor(q, 1);
    q += __shfl_xor(q, 2);
    q += __shfl_xor(q, 4);
    q += __shfl_xor(q, 8);
    if (row < NNODES) {
      HF4 o0, o1;
      o0.h2[0] = __floats2half2_rn(v[0], v[1]);
      o0.h2[1] = __floats2half2_rn(v[2], v[3]);
      o1.h2[0] = __floats2half2_rn(v[4], v[5]);
      o1.h2[1] = __floats2half2_rn(v[6], v[7]);
      *(float2*)(x1h + (size_t)row * DHID + tx * 4)      = o0.f;
      *(float2*)(x1h + (size_t)row * DHID + 64 + tx * 4) = o1.f;
      if (tx == 0) inv1[row] = 1.0f / fmaxf(sqrtf(q), 1e-12f);
    }
  }
}

// ---------------- fc2: out = x3 @ W2 + b2, 8 nodes/block (320 thr) -----------
__global__ __launch_bounds__(320) void fc2_kernel(
    const float* __restrict__ x3, const float* __restrict__ W2,
    const float* __restrict__ b2, float* __restrict__ out)
{
  __shared__ float Xs[8][DHID];      // 4 KB
  const int tid   = threadIdx.x;
  const int node0 = blockIdx.x * 8;
  for (int idx = tid; idx < 8 * DHID; idx += 320)
    Xs[idx >> 7][idx & 127] = x3[(size_t)node0 * DHID + idx];
  __syncthreads();

  const int ns = tid / NCLS;         // 0..7
  const int c  = tid - ns * NCLS;    // 0..39
  float acc = b2[c];
#pragma unroll 8
  for (int k = 0; k < DHID; ++k) acc += Xs[ns][k] * W2[k * NCLS + c];
  out[(size_t)(node0 + ns) * NCLS + c] = acc;
}

// ---------------- CSR build: deterministic two-pass multi-split --------------
// K1: per-(view,block) LDS histogram of a private edge chunk -> H[v][bkt][blk]
__global__ __launch_bounds__(256) void hist_part_kernel(
    const int* __restrict__ dst1, const int* __restrict__ dst2,
    int* __restrict__ H)
{
  const int bid = blockIdx.x;
  const int v   = bid >= PPART;
  const int p   = v ? bid - PPART : bid;
  const int* __restrict__ dst = v ? dst2 : dst1;

  __shared__ int hist[NBK];
  for (int i = threadIdx.x; i < NBK; i += 256) hist[i] = 0;
  __syncthreads();
  const int beg = p * CHUNK;
  const int end = (beg + CHUNK < NEDGES) ? beg + CHUNK : NEDGES;
  for (int j = beg + threadIdx.x; j < end; j += 256)
    atomicAdd(&hist[dst[j] >> 7], 1);
  __syncthreads();
  for (int i = threadIdx.x; i < NBK; i += 256)
    H[(v * NBK + i) * PPART + p] = hist[i];
}

// K2a: per-bucket exclusive scan of its 128 partition counts (in place) + total
__global__ __launch_bounds__(128) void scan_bucket_kernel(
    int* __restrict__ H, int* __restrict__ btot)
{
  const int b   = blockIdx.x;        // 0..2*NBK-1
  const int tid = threadIdx.x;
  __shared__ int sm[PPART];
  const int v = H[b * PPART + tid];
  sm[tid] = v;
  __syncthreads();
  for (int off = 1; off < PPART; off <<= 1) {
    int t = (tid >= off) ? sm[tid - off] : 0;
    __syncthreads();
    sm[tid] += t;
    __syncthreads();
  }
  H[b * PPART + tid] = sm[tid] - v;  // exclusive within bucket
  if (tid == PPART - 1) btot[b] = sm[tid];
}

// K2b: scan 2*NBK bucket totals -> boffG (global bucket bases)
__global__ __launch_bounds__(1024) void scan_btot_kernel(
    const int* __restrict__ btot, int* __restrict__ boffG)
{
  __shared__ int sm[1024];
  const int tid = threadIdx.x;
  const int v = (tid < 2 * NBK) ? btot[tid] : 0;
  sm[tid] = v;
  __syncthreads();
  for (int off = 1; off < 1024; off <<= 1) {
    int t = (tid >= off) ? sm[tid - off] : 0;
    __syncthreads();
    sm[tid] += t;
    __syncthreads();
  }
  if (tid < 2 * NBK) boffG[tid] = sm[tid] - v;
  if (tid == 0) boffG[2 * NBK] = 2 * NEDGES;
}

// K3: place edges at exact positions (LDS cursors only; writes cluster ~128B)
__global__ __launch_bounds__(256) void scatter_part_kernel(
    const int* __restrict__ src1, const int* __restrict__ dst1,
    const int* __restrict__ src2, const int* __restrict__ dst2,
    const int* __restrict__ H, const int* __restrict__ boffG,
    int2* __restrict__ st)
{
  const int bid = blockIdx.x;
  const int v   = bid >= PPART;
  const int p   = v ? bid - PPART : bid;
  const int* __restrict__ src = v ? src2 : src1;
  const int* __restrict__ dst = v ? dst2 : dst1;

  __shared__ int lcur[NBK];
  for (int i = threadIdx.x; i < NBK; i += 256)
    lcur[i] = boffG[v * NBK + i] + H[(v * NBK + i) * PPART + p];
  __syncthreads();
  const int beg = p * CHUNK;
  const int end = (beg + CHUNK < NEDGES) ? beg + CHUNK : NEDGES;
  for (int j = beg + threadIdx.x; j < end; j += 256) {
    const int s = src[j], d = dst[j];
    const int k = atomicAdd(&lcur[d >> 7], 1);
    st[k] = make_int2(s, d);
  }
}

// K4: per bucket: degrees -> rp, place srcs in LDS, sort segments (determinism),
//     coalesced col write.
__global__ __launch_bounds__(256) void build_buckets_kernel(
    const int2* __restrict__ st, const int* __restrict__ boffG,
    int* __restrict__ rp1, int* __restrict__ rp2,
    int* __restrict__ col1, int* __restrict__ col2)
{
  const int bid = blockIdx.x;
  const int v   = bid >= NBK;
  const int b   = v ? bid - NBK : bid;
  int* __restrict__ rp  = v ? rp2 : rp1;
  int* __restrict__ col = v ? col2 : col1;
  const int tid = threadIdx.x;

  const int off0G  = boffG[bid];
  const int cnt    = boffG[bid + 1] - off0G;
  const int off0   = off0G - v * NEDGES;    // view-local offset
  const int base_d = b * BW;
  const int nd     = (NNODES - base_d < BW) ? (NNODES - base_d) : BW;

  __shared__ int deg[BW];
  __shared__ int loff[BW + 1];
  __shared__ int cur[BW];
  __shared__ int lcol[CAP];

  if (tid < BW) deg[tid] = 0;
  __syncthreads();
  for (int j = tid; j < cnt; j += 256)
    atomicAdd(&deg[st[off0G + j].y - base_d], 1);
  __syncthreads();

  if (tid == 0) loff[0] = 0;
  if (tid < BW) loff[tid + 1] = deg[tid];
  __syncthreads();
  for (int off = 1; off < BW; off <<= 1) {
    int t = (tid < BW && tid + 1 >= off) ? loff[tid + 1 - off] : 0;
    __syncthreads();
    if (tid < BW && tid + 1 >= off) loff[tid + 1] += t;
    __syncthreads();
  }
  if (tid < nd) rp[base_d + tid] = off0 + loff[tid];
  if (tid == 0 && b == NBK - 1) rp[NNODES] = NEDGES;
  if (tid < BW) cur[tid] = loff[tid];
  __syncthreads();

  if (cnt <= CAP) {
    for (int j = tid; j < cnt; j += 256) {
      const int2 pr = st[off0G + j];
      const int k = atomicAdd(&cur[pr.y - base_d], 1);
      lcol[k] = pr.x;
    }
    __syncthreads();
    if (tid < nd) {                   // sort own segment ascending (in LDS)
      const int s0 = loff[tid], s1 = s0 + deg[tid];
      for (int a = s0 + 1; a < s1; ++a) {
        const int key = lcol[a];
        int c = a - 1;
        while (c >= s0 && lcol[c] > key) { lcol[c + 1] = lcol[c]; --c; }
        lcol[c + 1] = key;
      }
    }
    __syncthreads();
    for (int j = tid; j < cnt; j += 256) col[off0 + j] = lcol[j];
  } else {                            // overflow fallback (never for random data)
    for (int j = tid; j < cnt; j += 256) {
      const int2 pr = st[off0G + j];
      const int k = atomicAdd(&cur[pr.y - base_d], 1);
      col[off0 + k] = pr.x;
    }
    __syncthreads();
    if (tid < nd) {
      const int s0 = off0 + loff[tid], s1 = s0 + deg[tid];
      for (int a = s0 + 1; a < s1; ++a) {
        const int key = col[a];
        int c = a - 1;
        while (c >= s0 && col[c] > key) { col[c + 1] = col[c]; --c; }
        col[c + 1] = key;
      }
    }
  }
}

// ---------------- AGNN layer: fused views, fp16 feature gathers --------------
// 16-lane groups (4 edges/view in flight, 8 dims/lane, one 16 B fp16 load per
// view per lane). Dots/aggregation accumulate fp32. Branchless round loop with
// col prefetch. softmax shift-invariance: w = exp(e) directly.
__global__ __launch_bounds__(256) void agnn_layer_kernel(
    const __half* __restrict__ xh, const float* __restrict__ inv,
    const int* __restrict__ rp1, const int* __restrict__ col1,
    const int* __restrict__ rp2, const int* __restrict__ col2,
    const float* __restrict__ beta_p, const float* __restrict__ order_attn,
    __half* __restrict__ yh_out, float* __restrict__ inv_out,
    float* __restrict__ y32_out, int n)
{
  const int wid  = (blockIdx.x * blockDim.x + threadIdx.x) >> 6;
  if (wid >= n) return;
  const int lane = threadIdx.x & 63;
  const int grp  = lane >> 4;        // 0..3  : edge slot within each view
  const int sub  = lane & 15;        // 0..15 : 8 dims each -> 128 dims

  const float beta = beta_p[0];
  const float bi   = beta * inv[wid];

  HF8 ud; ud.f = *(const float4*)(xh + (size_t)wid * DHID + sub * 8);
  float xd[8];
#pragma unroll
  for (int i = 0; i < 4; ++i) {
    const float2 t = __half22float2(ud.h2[i]);
    xd[2 * i] = t.x; xd[2 * i + 1] = t.y;
  }

  const int beg1 = rp1[wid], end1 = rp1[wid + 1];
  const int beg2 = rp2[wid], end2 = rp2[wid + 1];

  float s1 = 0.f, s2 = 0.f;
  float y1[8], y2[8];
#pragma unroll
  for (int k = 0; k < 8; ++k) { y1[k] = 0.f; y2[k] = 0.f; }

  int j1 = beg1 + grp, j2 = beg2 + grp;
  int sa1 = col1[j1 < end1 ? j1 : 0];
  int sa2 = col2[j2 < end2 ? j2 : 0];

  while (j1 < end1 || j2 < end2) {
    const bool p1 = j1 < end1;
    const bool p2 = j2 < end2;
    const int  c1 = sa1, c2 = sa2;

    const float isa1 = inv[c1];
    const float isa2 = inv[c2];
    HF8 u1; u1.f = *(const float4*)(xh + (size_t)c1 * DHID + sub * 8);
    HF8 u2; u2.f = *(const float4*)(xh + (size_t)c2 * DHID + sub * 8);

    const int nj1 = j1 + 4, nj2 = j2 + 4;
    sa1 = col1[nj1 < end1 ? nj1 : 0];
    sa2 = col2[nj2 < end2 ? nj2 : 0];

    float av[8], bv[8];
#pragma unroll
    for (int i = 0; i < 4; ++i) {
      const float2 ta = __half22float2(u1.h2[i]);
      const float2 tb = __half22float2(u2.h2[i]);
      av[2 * i] = ta.x; av[2 * i + 1] = ta.y;
      bv[2 * i] = tb.x; bv[2 * i + 1] = tb.y;
    }

    float d1 = 0.f, d2 = 0.f;
#pragma unroll
    for (int k = 0; k < 8; ++k) { d1 += av[k] * xd[k]; d2 += bv[k] * xd[k]; }
#pragma unroll
    for (int off = 1; off <= 8; off <<= 1) {
      d1 += __shfl_xor(d1, off);
      d2 += __shfl_xor(d2, off);
    }

    const float w1 = p1 ? __expf(bi * isa1 * d1) : 0.f;
    const float w2 = p2 ? __expf(bi * isa2 * d2) : 0.f;
    s1 += w1; s2 += w2;
#pragma unroll
    for (int k = 0; k < 8; ++k) {
      y1[k] += w1 * av[k];
      y2[k] += w2 * bv[k];
    }

    j1 = nj1; j2 = nj2;
  }

  s1 += __shfl_xor(s1, 16); s1 += __shfl_xor(s1, 32);
  s2 += __shfl_xor(s2, 16); s2 += __shfl_xor(s2, 32);
#pragma unroll
  for (int k = 0; k < 8; ++k) {
    y1[k] += __shfl_xor(y1[k], 16); y1[k] += __shfl_xor(y1[k], 32);
    y2[k] += __shfl_xor(y2[k], 16); y2[k] += __shfl_xor(y2[k], 32);
  }

  const float r1 = (end1 > beg1) ? order_attn[0] / fmaxf(s1, 1e-12f) : 0.f;
  const float r2 = (end2 > beg2) ? order_attn[1] / fmaxf(s2, 1e-12f) : 0.f;
  float acc[8];
#pragma unroll
  for (int k = 0; k < 8; ++k) acc[k] = r1 * y1[k] + r2 * y2[k];

  if (inv_out) {                     // fused row-norm (fp32, pre-rounding)
    float ss = 0.f;
#pragma unroll
    for (int k = 0; k < 8; ++k) ss += acc[k] * acc[k];
    ss += __shfl_xor(ss, 1);
    ss += __shfl_xor(ss, 2);
    ss += __shfl_xor(ss, 4);
    ss += __shfl_xor(ss, 8);
    if (lane == 0) inv_out[wid] = 1.0f / fmaxf(sqrtf(ss), 1e-12f);
  }

  if (grp == 0) {
    if (yh_out) {
      HF8 o;
      o.h2[0] = __floats2half2_rn(acc[0], acc[1]);
      o.h2[1] = __floats2half2_rn(acc[2], acc[3]);
      o.h2[2] = __floats2half2_rn(acc[4], acc[5]);
      o.h2[3] = __floats2half2_rn(acc[6], acc[7]);
      *(float4*)(yh_out + (size_t)wid * DHID + sub * 8) = o.f;
    }
    if (y32_out) {
      float* yp = y32_out + (size_t)wid * DHID + sub * 8;
      *(float4*)(yp)     = make_float4(acc[0], acc[1], acc[2], acc[3]);
      *(float4*)(yp + 4) = make_float4(acc[4], acc[5], acc[6], acc[7]);
    }
  }
}

// ---------------- launcher ----------------------------------------------------
extern "C" void kernel_launch(void* const* d_in, const int* in_sizes, int n_in,
                              void* d_out, int out_size, void* d_ws, size_t ws_size,
                              hipStream_t stream)
{
  const float* X          = (const float*)d_in[0];
  const int*   src1       = (const int*)d_in[1];
  const int*   dst1       = (const int*)d_in[2];
  const int*   src2       = (const int*)d_in[3];
  const int*   dst2       = (const int*)d_in[4];
  const float* order_attn = (const float*)d_in[5];
  const float* W1         = (const float*)d_in[6];
  const float* b1         = (const float*)d_in[7];
  const float* W2         = (const float*)d_in[8];
  const float* b2         = (const float*)d_in[9];
  const float* beta1      = (const float*)d_in[10];
  const float* beta2      = (const float*)d_in[11];
  float*       out        = (float*)d_out;

  char*  ws  = (char*)d_ws;
  size_t off = 0;
  auto alloc = [&](size_t bytes) -> void* {
    void* p = ws + off;
    off += (bytes + 255) & ~size_t(255);
    return p;
  };
  __half* x1h  = (__half*)alloc((size_t)NNODES * DHID * 2);
  __half* x2h  = (__half*)alloc((size_t)NNODES * DHID * 2);
  float*  x3   = (float*)alloc((size_t)NNODES * DHID * 4);
  float*  inv1 = (float*)alloc((size_t)NNODES * 4);
  float*  inv2 = (float*)alloc((size_t)NNODES * 4);
  int*    rp1  = (int*)alloc((size_t)(NNODES + 1) * 4);
  int*    rp2  = (int*)alloc((size_t)(NNODES + 1) * 4);
  int*    col1 = (int*)alloc((size_t)NEDGES * 4);
  int*    col2 = (int*)alloc((size_t)NEDGES * 4);
  int*    H    = (int*)alloc((size_t)2 * NBK * PPART * 4);
  int*    btot = (int*)alloc((size_t)2 * NBK * 4);
  int*    boffG= (int*)alloc((size_t)(2 * NBK + 1) * 4);
  // staging overlays x3 (12.8 MB <= 25.6 MB): x3 written only by layer2,
  // after build_buckets has consumed st.
  int2*   st   = (int2*)x3;

  const int WB = (NNODES + 3) / 4;   // 4 waves (nodes) per 256-thread block

  // CSR for both views (reused by both layers); no global atomics, segments
  // sorted in LDS -> fully deterministic across replays.
  hist_part_kernel<<<2 * PPART, 256, 0, stream>>>(dst1, dst2, H);
  scan_bucket_kernel<<<2 * NBK, 128, 0, stream>>>(H, btot);
  scan_btot_kernel<<<1, 1024, 0, stream>>>(btot, boffG);
  scatter_part_kernel<<<2 * PPART, 256, 0, stream>>>(src1, dst1, src2, dst2,
                                                     H, boffG, st);
  build_buckets_kernel<<<2 * NBK, 256, 0, stream>>>(st, boffG, rp1, rp2, col1, col2);

  fc1_kernel<<<(NNODES + 63) / 64, 256, 0, stream>>>(X, W1, b1, x1h, inv1);

  agnn_layer_kernel<<<WB, 256, 0, stream>>>(x1h, inv1, rp1, col1, rp2, col2,
                                            beta1, order_attn,
                                            x2h, inv2, nullptr, NNODES);
  agnn_layer_kernel<<<WB, 256, 0, stream>>>(x2h, inv2, rp1, col1, rp2, col2,
                                            beta2, order_attn,
                                            nullptr, nullptr, x3, NNODES);

  fc2_kernel<<<NNODES / 8, 320, 0, stream>>>(x3, W2, b2, out);
}

// Round 11
// 300.417 us; speedup vs baseline: 1.4589x; 1.0119x over previous
//
#include <hip/hip_runtime.h>
#include <hip/hip_fp16.h>
#include <math.h>

#define NNODES 50000
#define NEDGES 800000
#define DIN    256
#define DHID   128
#define NCLS   40

#define BW    128                    // dst values per bucket
#define NBK   391                    // ceil(NNODES / BW)
#define CAP   6144                   // LDS col capacity per bucket (mean 2048, sd ~45)
#define PPART 128                    // partition blocks per view
#define CHUNK 6250                   // NEDGES / PPART

typedef _Float16 h2v __attribute__((ext_vector_type(2)));
union HF8 { float4 f; __half2 h2[4]; h2v v[4]; };   // 8 fp16 <-> 16 B
union HF4 { float2 f; __half2 h2[2]; };             // 4 fp16 <-> 8 B

// ---------------- fc1: register-blocked GEMM + fused relu/fp16/row-norm ------
// 64 nodes x 128 cols per 256-thread block; thread = 4m x 8n outer product.
__global__ __launch_bounds__(256) void fc1_kernel(
    const float* __restrict__ X, const float* __restrict__ W1,
    const float* __restrict__ b1, __half* __restrict__ x1h,
    float* __restrict__ inv1)
{
  __shared__ float As[64][65];       // X^T tile [k][m], padded
  __shared__ float Bs[64][132];      // W1 tile [k][n], padded
  const int tid   = threadIdx.x;
  const int node0 = blockIdx.x * 64;
  const int tx    = tid & 15;        // n-groups: cols {tx*4..+3} u {64+tx*4..+3}
  const int ty    = tid >> 4;        // m-group: rows ty*4..+3

  const int ml   = tid >> 2;         // 0..63 : staging row
  const int kq   = tid & 3;
  const int mrow = (node0 + ml < NNODES) ? node0 + ml : NNODES - 1;  // clamp

  float acc[4][8];
#pragma unroll
  for (int i = 0; i < 4; ++i)
#pragma unroll
    for (int j = 0; j < 8; ++j) acc[i][j] = 0.f;

  for (int kt = 0; kt < 4; ++kt) {
    const int k0 = kt * 64;
#pragma unroll
    for (int q = 0; q < 4; ++q) {
      const int kk = kq * 16 + q * 4;
      const float4 v = *(const float4*)(X + (size_t)mrow * DIN + k0 + kk);
      As[kk + 0][ml] = v.x; As[kk + 1][ml] = v.y;
      As[kk + 2][ml] = v.z; As[kk + 3][ml] = v.w;
    }
#pragma unroll
    for (int q = 0; q < 8; ++q) {
      const int flat = q * 1024 + tid * 4;
      const int kk = flat >> 7, nn = flat & 127;
      *(float4*)&Bs[kk][nn] = *(const float4*)(W1 + (size_t)(k0 + kk) * DHID + nn);
    }
    __syncthreads();

#pragma unroll 4
    for (int k = 0; k < 64; ++k) {
      const float4 a  = *(const float4*)&As[k][ty * 4];
      const float4 b0 = *(const float4*)&Bs[k][tx * 4];
      const float4 b1v= *(const float4*)&Bs[k][64 + tx * 4];
      const float av[4] = {a.x, a.y, a.z, a.w};
      const float bv[8] = {b0.x, b0.y, b0.z, b0.w, b1v.x, b1v.y, b1v.z, b1v.w};
#pragma unroll
      for (int i = 0; i < 4; ++i)
#pragma unroll
        for (int j = 0; j < 8; ++j) acc[i][j] += av[i] * bv[j];
    }
    __syncthreads();
  }

  const float4 bb0 = *(const float4*)(b1 + tx * 4);
  const float4 bb1 = *(const float4*)(b1 + 64 + tx * 4);
  const float bias[8] = {bb0.x, bb0.y, bb0.z, bb0.w, bb1.x, bb1.y, bb1.z, bb1.w};

#pragma unroll
  for (int i = 0; i < 4; ++i) {
    const int row = node0 + ty * 4 + i;
    float v[8];
    float q = 0.f;
#pragma unroll
    for (int j = 0; j < 8; ++j) {
      float t = acc[i][j] + bias[j];
      t = t > 0.f ? t : 0.f;
      v[j] = t;
      q += t * t;
    }
    q += __shfl_xor(q, 1);
    q += __shfl_xor(q, 2);
    q += __shfl_xor(q, 4);
    q += __shfl_xor(q, 8);
    if (row < NNODES) {
      HF4 o0, o1;
      o0.h2[0] = __floats2half2_rn(v[0], v[1]);
      o0.h2[1] = __floats2half2_rn(v[2], v[3]);
      o1.h2[0] = __floats2half2_rn(v[4], v[5]);
      o1.h2[1] = __floats2half2_rn(v[6], v[7]);
      *(float2*)(x1h + (size_t)row * DHID + tx * 4)      = o0.f;
      *(float2*)(x1h + (size_t)row * DHID + 64 + tx * 4) = o1.f;
      if (tx == 0) inv1[row] = 1.0f / fmaxf(sqrtf(q), 1e-12f);
    }
  }
}

// ---------------- fc2: out = x3 @ W2 + b2, 8 nodes/block (320 thr) -----------
__global__ __launch_bounds__(320) void fc2_kernel(
    const float* __restrict__ x3, const float* __restrict__ W2,
    const float* __restrict__ b2, float* __restrict__ out)
{
  __shared__ float Xs[8][DHID];      // 4 KB
  const int tid   = threadIdx.x;
  const int node0 = blockIdx.x * 8;
  for (int idx = tid; idx < 8 * DHID; idx += 320)
    Xs[idx >> 7][idx & 127] = x3[(size_t)node0 * DHID + idx];
  __syncthreads();

  const int ns = tid / NCLS;         // 0..7
  const int c  = tid - ns * NCLS;    // 0..39
  float acc = b2[c];
#pragma unroll 8
  for (int k = 0; k < DHID; ++k) acc += Xs[ns][k] * W2[k * NCLS + c];
  out[(size_t)(node0 + ns) * NCLS + c] = acc;
}

// ---------------- CSR build: deterministic two-pass multi-split --------------
__global__ __launch_bounds__(256) void hist_part_kernel(
    const int* __restrict__ dst1, const int* __restrict__ dst2,
    int* __restrict__ H)
{
  const int bid = blockIdx.x;
  const int v   = bid >= PPART;
  const int p   = v ? bid - PPART : bid;
  const int* __restrict__ dst = v ? dst2 : dst1;

  __shared__ int hist[NBK];
  for (int i = threadIdx.x; i < NBK; i += 256) hist[i] = 0;
  __syncthreads();
  const int beg = p * CHUNK;
  const int end = (beg + CHUNK < NEDGES) ? beg + CHUNK : NEDGES;
  for (int j = beg + threadIdx.x; j < end; j += 256)
    atomicAdd(&hist[dst[j] >> 7], 1);
  __syncthreads();
  for (int i = threadIdx.x; i < NBK; i += 256)
    H[(v * NBK + i) * PPART + p] = hist[i];
}

__global__ __launch_bounds__(128) void scan_bucket_kernel(
    int* __restrict__ H, int* __restrict__ btot)
{
  const int b   = blockIdx.x;        // 0..2*NBK-1
  const int tid = threadIdx.x;
  __shared__ int sm[PPART];
  const int v = H[b * PPART + tid];
  sm[tid] = v;
  __syncthreads();
  for (int off = 1; off < PPART; off <<= 1) {
    int t = (tid >= off) ? sm[tid - off] : 0;
    __syncthreads();
    sm[tid] += t;
    __syncthreads();
  }
  H[b * PPART + tid] = sm[tid] - v;  // exclusive within bucket
  if (tid == PPART - 1) btot[b] = sm[tid];
}

__global__ __launch_bounds__(1024) void scan_btot_kernel(
    const int* __restrict__ btot, int* __restrict__ boffG)
{
  __shared__ int sm[1024];
  const int tid = threadIdx.x;
  const int v = (tid < 2 * NBK) ? btot[tid] : 0;
  sm[tid] = v;
  __syncthreads();
  for (int off = 1; off < 1024; off <<= 1) {
    int t = (tid >= off) ? sm[tid - off] : 0;
    __syncthreads();
    sm[tid] += t;
    __syncthreads();
  }
  if (tid < 2 * NBK) boffG[tid] = sm[tid] - v;
  if (tid == 0) boffG[2 * NBK] = 2 * NEDGES;
}

__global__ __launch_bounds__(256) void scatter_part_kernel(
    const int* __restrict__ src1, const int* __restrict__ dst1,
    const int* __restrict__ src2, const int* __restrict__ dst2,
    const int* __restrict__ H, const int* __restrict__ boffG,
    int2* __restrict__ st)
{
  const int bid = blockIdx.x;
  const int v   = bid >= PPART;
  const int p   = v ? bid - PPART : bid;
  const int* __restrict__ src = v ? src2 : src1;
  const int* __restrict__ dst = v ? dst2 : dst1;

  __shared__ int lcur[NBK];
  for (int i = threadIdx.x; i < NBK; i += 256)
    lcur[i] = boffG[v * NBK + i] + H[(v * NBK + i) * PPART + p];
  __syncthreads();
  const int beg = p * CHUNK;
  const int end = (beg + CHUNK < NEDGES) ? beg + CHUNK : NEDGES;
  for (int j = beg + threadIdx.x; j < end; j += 256) {
    const int s = src[j], d = dst[j];
    const int k = atomicAdd(&lcur[d >> 7], 1);
    st[k] = make_int2(s, d);
  }
}

__global__ __launch_bounds__(256) void build_buckets_kernel(
    const int2* __restrict__ st, const int* __restrict__ boffG,
    int* __restrict__ rp1, int* __restrict__ rp2,
    int* __restrict__ col1, int* __restrict__ col2)
{
  const int bid = blockIdx.x;
  const int v   = bid >= NBK;
  const int b   = v ? bid - NBK : bid;
  int* __restrict__ rp  = v ? rp2 : rp1;
  int* __restrict__ col = v ? col2 : col1;
  const int tid = threadIdx.x;

  const int off0G  = boffG[bid];
  const int cnt    = boffG[bid + 1] - off0G;
  const int off0   = off0G - v * NEDGES;    // view-local offset
  const int base_d = b * BW;
  const int nd     = (NNODES - base_d < BW) ? (NNODES - base_d) : BW;

  __shared__ int deg[BW];
  __shared__ int loff[BW + 1];
  __shared__ int cur[BW];
  __shared__ int lcol[CAP];

  if (tid < BW) deg[tid] = 0;
  __syncthreads();
  for (int j = tid; j < cnt; j += 256)
    atomicAdd(&deg[st[off0G + j].y - base_d], 1);
  __syncthreads();

  if (tid == 0) loff[0] = 0;
  if (tid < BW) loff[tid + 1] = deg[tid];
  __syncthreads();
  for (int off = 1; off < BW; off <<= 1) {
    int t = (tid < BW && tid + 1 >= off) ? loff[tid + 1 - off] : 0;
    __syncthreads();
    if (tid < BW && tid + 1 >= off) loff[tid + 1] += t;
    __syncthreads();
  }
  if (tid < nd) rp[base_d + tid] = off0 + loff[tid];
  if (tid == 0 && b == NBK - 1) rp[NNODES] = NEDGES;
  if (tid < BW) cur[tid] = loff[tid];
  __syncthreads();

  if (cnt <= CAP) {
    for (int j = tid; j < cnt; j += 256) {
      const int2 pr = st[off0G + j];
      const int k = atomicAdd(&cur[pr.y - base_d], 1);
      lcol[k] = pr.x;
    }
    __syncthreads();
    if (tid < nd) {                   // sort own segment ascending (in LDS)
      const int s0 = loff[tid], s1 = s0 + deg[tid];
      for (int a = s0 + 1; a < s1; ++a) {
        const int key = lcol[a];
        int c = a - 1;
        while (c >= s0 && lcol[c] > key) { lcol[c + 1] = lcol[c]; --c; }
        lcol[c + 1] = key;
      }
    }
    __syncthreads();
    for (int j = tid; j < cnt; j += 256) col[off0 + j] = lcol[j];
  } else {                            // overflow fallback (never for random data)
    for (int j = tid; j < cnt; j += 256) {
      const int2 pr = st[off0G + j];
      const int k = atomicAdd(&cur[pr.y - base_d], 1);
      col[off0 + k] = pr.x;
    }
    __syncthreads();
    if (tid < nd) {
      const int s0 = off0 + loff[tid], s1 = s0 + deg[tid];
      for (int a = s0 + 1; a < s1; ++a) {
        const int key = col[a];
        int c = a - 1;
        while (c >= s0 && col[c] > key) { col[c + 1] = col[c]; --c; }
        col[c + 1] = key;
      }
    }
  }
}

// ---------------- AGNN layer: fused views, fp16 gathers, dot2/fma_mix --------
// 16-lane groups (4 edges/view in flight, 8 dims/lane). Dot via
// v_dot2_f32_f16 (fp16 pairs -> fp32, exact products); aggregation via the
// v_fma_mix_f32 pattern fmaf(w, (float)h, acc) -> fp32 accumulation with no
// separate cvt instructions. Branchless round loop with col prefetch.
// softmax shift-invariance: w = exp(e) directly.
__global__ __launch_bounds__(256) void agnn_layer_kernel(
    const __half* __restrict__ xh, const float* __restrict__ inv,
    const int* __restrict__ rp1, const int* __restrict__ col1,
    const int* __restrict__ rp2, const int* __restrict__ col2,
    const float* __restrict__ beta_p, const float* __restrict__ order_attn,
    __half* __restrict__ yh_out, float* __restrict__ inv_out,
    float* __restrict__ y32_out, int n)
{
  const int wid  = (blockIdx.x * blockDim.x + threadIdx.x) >> 6;
  if (wid >= n) return;
  const int lane = threadIdx.x & 63;
  const int grp  = lane >> 4;        // 0..3  : edge slot within each view
  const int sub  = lane & 15;        // 0..15 : 8 dims each -> 128 dims

  const float beta = beta_p[0];
  const float bi   = beta * inv[wid];

  HF8 ud; ud.f = *(const float4*)(xh + (size_t)wid * DHID + sub * 8);  // stays fp16

  const int beg1 = rp1[wid], end1 = rp1[wid + 1];
  const int beg2 = rp2[wid], end2 = rp2[wid + 1];

  float s1 = 0.f, s2 = 0.f;
  float y1[8], y2[8];
#pragma unroll
  for (int k = 0; k < 8; ++k) { y1[k] = 0.f; y2[k] = 0.f; }

  int j1 = beg1 + grp, j2 = beg2 + grp;
  int sa1 = col1[j1 < end1 ? j1 : 0];
  int sa2 = col2[j2 < end2 ? j2 : 0];

  while (j1 < end1 || j2 < end2) {
    const bool p1 = j1 < end1;
    const bool p2 = j2 < end2;
    const int  c1 = sa1, c2 = sa2;

    const float isa1 = inv[c1];
    const float isa2 = inv[c2];
    HF8 u1; u1.f = *(const float4*)(xh + (size_t)c1 * DHID + sub * 8);
    HF8 u2; u2.f = *(const float4*)(xh + (size_t)c2 * DHID + sub * 8);

    const int nj1 = j1 + 4, nj2 = j2 + 4;
    sa1 = col1[nj1 < end1 ? nj1 : 0];
    sa2 = col2[nj2 < end2 ? nj2 : 0];

    // dot via v_dot2_f32_f16: 4 instrs per view, no converts
    float d1 = 0.f, d2 = 0.f;
#pragma unroll
    for (int i = 0; i < 4; ++i) {
      d1 = __builtin_amdgcn_fdot2(u1.v[i], ud.v[i], d1, false);
      d2 = __builtin_amdgcn_fdot2(u2.v[i], ud.v[i], d2, false);
    }
#pragma unroll
    for (int off = 1; off <= 8; off <<= 1) {
      d1 += __shfl_xor(d1, off);
      d2 += __shfl_xor(d2, off);
    }

    const float w1 = p1 ? __expf(bi * isa1 * d1) : 0.f;
    const float w2 = p2 ? __expf(bi * isa2 * d2) : 0.f;
    s1 += w1; s2 += w2;
    // aggregation via v_fma_mix_f32 pattern: fp32 acc, fp16 operand, no cvt
#pragma unroll
    for (int i = 0; i < 4; ++i) {
      y1[2 * i + 0] = fmaf(w1, (float)u1.v[i][0], y1[2 * i + 0]);
      y1[2 * i + 1] = fmaf(w1, (float)u1.v[i][1], y1[2 * i + 1]);
      y2[2 * i + 0] = fmaf(w2, (float)u2.v[i][0], y2[2 * i + 0]);
      y2[2 * i + 1] = fmaf(w2, (float)u2.v[i][1], y2[2 * i + 1]);
    }

    j1 = nj1; j2 = nj2;
  }

  s1 += __shfl_xor(s1, 16); s1 += __shfl_xor(s1, 32);
  s2 += __shfl_xor(s2, 16); s2 += __shfl_xor(s2, 32);
#pragma unroll
  for (int k = 0; k < 8; ++k) {
    y1[k] += __shfl_xor(y1[k], 16); y1[k] += __shfl_xor(y1[k], 32);
    y2[k] += __shfl_xor(y2[k], 16); y2[k] += __shfl_xor(y2[k], 32);
  }

  const float r1 = (end1 > beg1) ? order_attn[0] / fmaxf(s1, 1e-12f) : 0.f;
  const float r2 = (end2 > beg2) ? order_attn[1] / fmaxf(s2, 1e-12f) : 0.f;
  float acc[8];
#pragma unroll
  for (int k = 0; k < 8; ++k) acc[k] = r1 * y1[k] + r2 * y2[k];

  if (inv_out) {                     // fused row-norm (fp32, pre-rounding)
    float ss = 0.f;
#pragma unroll
    for (int k = 0; k < 8; ++k) ss += acc[k] * acc[k];
    ss += __shfl_xor(ss, 1);
    ss += __shfl_xor(ss, 2);
    ss += __shfl_xor(ss, 4);
    ss += __shfl_xor(ss, 8);
    if (lane == 0) inv_out[wid] = 1.0f / fmaxf(sqrtf(ss), 1e-12f);
  }

  if (grp == 0) {
    if (yh_out) {
      HF8 o;
      o.h2[0] = __floats2half2_rn(acc[0], acc[1]);
      o.h2[1] = __floats2half2_rn(acc[2], acc[3]);
      o.h2[2] = __floats2half2_rn(acc[4], acc[5]);
      o.h2[3] = __floats2half2_rn(acc[6], acc[7]);
      *(float4*)(yh_out + (size_t)wid * DHID + sub * 8) = o.f;
    }
    if (y32_out) {
      float* yp = y32_out + (size_t)wid * DHID + sub * 8;
      *(float4*)(yp)     = make_float4(acc[0], acc[1], acc[2], acc[3]);
      *(float4*)(yp + 4) = make_float4(acc[4], acc[5], acc[6], acc[7]);
    }
  }
}

// ---------------- launcher ----------------------------------------------------
extern "C" void kernel_launch(void* const* d_in, const int* in_sizes, int n_in,
                              void* d_out, int out_size, void* d_ws, size_t ws_size,
                              hipStream_t stream)
{
  const float* X          = (const float*)d_in[0];
  const int*   src1       = (const int*)d_in[1];
  const int*   dst1       = (const int*)d_in[2];
  const int*   src2       = (const int*)d_in[3];
  const int*   dst2       = (const int*)d_in[4];
  const float* order_attn = (const float*)d_in[5];
  const float* W1         = (const float*)d_in[6];
  const float* b1         = (const float*)d_in[7];
  const float* W2         = (const float*)d_in[8];
  const float* b2         = (const float*)d_in[9];
  const float* beta1      = (const float*)d_in[10];
  const float* beta2      = (const float*)d_in[11];
  float*       out        = (float*)d_out;

  char*  ws  = (char*)d_ws;
  size_t off = 0;
  auto alloc = [&](size_t bytes) -> void* {
    void* p = ws + off;
    off += (bytes + 255) & ~size_t(255);
    return p;
  };
  __half* x1h  = (__half*)alloc((size_t)NNODES * DHID * 2);
  __half* x2h  = (__half*)alloc((size_t)NNODES * DHID * 2);
  float*  x3   = (float*)alloc((size_t)NNODES * DHID * 4);
  float*  inv1 = (float*)alloc((size_t)NNODES * 4);
  float*  inv2 = (float*)alloc((size_t)NNODES * 4);
  int*    rp1  = (int*)alloc((size_t)(NNODES + 1) * 4);
  int*    rp2  = (int*)alloc((size_t)(NNODES + 1) * 4);
  int*    col1 = (int*)alloc((size_t)NEDGES * 4);
  int*    col2 = (int*)alloc((size_t)NEDGES * 4);
  int*    H    = (int*)alloc((size_t)2 * NBK * PPART * 4);
  int*    btot = (int*)alloc((size_t)2 * NBK * 4);
  int*    boffG= (int*)alloc((size_t)(2 * NBK + 1) * 4);
  // staging overlays x3 (12.8 MB <= 25.6 MB): x3 written only by layer2,
  // after build_buckets has consumed st.
  int2*   st   = (int2*)x3;

  const int WB = (NNODES + 3) / 4;   // 4 waves (nodes) per 256-thread block

  hist_part_kernel<<<2 * PPART, 256, 0, stream>>>(dst1, dst2, H);
  scan_bucket_kernel<<<2 * NBK, 128, 0, stream>>>(H, btot);
  scan_btot_kernel<<<1, 1024, 0, stream>>>(btot, boffG);
  scatter_part_kernel<<<2 * PPART, 256, 0, stream>>>(src1, dst1, src2, dst2,
                                                     H, boffG, st);
  build_buckets_kernel<<<2 * NBK, 256, 0, stream>>>(st, boffG, rp1, rp2, col1, col2);

  fc1_kernel<<<(NNODES + 63) / 64, 256, 0, stream>>>(X, W1, b1, x1h, inv1);

  agnn_layer_kernel<<<WB, 256, 0, stream>>>(x1h, inv1, rp1, col1, rp2, col2,
                                            beta1, order_attn,
                                            x2h, inv2, nullptr, NNODES);
  agnn_layer_kernel<<<WB, 256, 0, stream>>>(x2h, inv2, rp1, col1, rp2, col2,
                                            beta2, order_attn,
                                            nullptr, nullptr, x3, NNODES);

  fc2_kernel<<<NNODES / 8, 320, 0, stream>>>(x3, W2, b2, out);
}